// Round 10
// baseline (590.049 us; speedup 1.0000x reference)
//
#include <hip/hip_runtime.h>
#include <hip/hip_cooperative_groups.h>
#include <cstdint>
#include <cstddef>

namespace cg = cooperative_groups;

// Problem constants (B=4, S=2048, D=1024)
#define DD 1024
#define SSEQ 2048
#define NB 4
#define MROWS 8192          // B*S
#define FBINS 513           // rfft bins for N=1024
#define FPAD 520            // padded row stride for Scum buffer
#define WFP 1152            // per-projection padded fp32 column count (9 tiles)
#define NQKV 3456           // 3 * WFP = 27 tiles of 128
#define NHID 4096
#define NCHUNK 64           // scan chunks over S
#define SCHUNK 32           // S per chunk

typedef _Float16 f16_t;
typedef _Float16 f16x8 __attribute__((ext_vector_type(8)));
typedef _Float16 f16x2 __attribute__((ext_vector_type(2)));
typedef float f32x4 __attribute__((ext_vector_type(4)));

__device__ __forceinline__ float2 cmul(float2 a, float2 b) {
  return make_float2(a.x * b.x - a.y * b.y, a.x * b.y + a.y * b.x);
}

// Async global->LDS 16B copy (m97: width=16 emits global_load_lds_dwordx4).
__device__ __forceinline__ void async_cp16(const void* g, void* l) {
  __builtin_amdgcn_global_load_lds(
      (const __attribute__((address_space(1))) void*)g,
      (__attribute__((address_space(3))) void*)l, 16, 0, 0);
}

// Counted vmcnt waits (T4): literal immediates via specialization.
template <int N> __device__ __forceinline__ void vwait();
template <> __device__ __forceinline__ void vwait<0>() { asm volatile("s_waitcnt vmcnt(0)" ::: "memory"); }
template <> __device__ __forceinline__ void vwait<1>() { asm volatile("s_waitcnt vmcnt(1)" ::: "memory"); }
template <> __device__ __forceinline__ void vwait<2>() { asm volatile("s_waitcnt vmcnt(2)" ::: "memory"); }
template <> __device__ __forceinline__ void vwait<3>() { asm volatile("s_waitcnt vmcnt(3)" ::: "memory"); }
template <> __device__ __forceinline__ void vwait<4>() { asm volatile("s_waitcnt vmcnt(4)" ::: "memory"); }

// Branchless erf-based gelu, A&S 7.1.26 (|eps_erf| <= 1.5e-7).
__device__ __forceinline__ float fast_gelu(float val) {
  float av = __builtin_fabsf(val);
  float z = av * 0.70710678118654752f;
  float t = __builtin_amdgcn_rcpf(__builtin_fmaf(0.3275911f, z, 1.0f));
  float poly = t * __builtin_fmaf(t,
      __builtin_fmaf(t, __builtin_fmaf(t,
          __builtin_fmaf(t, 1.061405429f, -1.453152027f),
          1.421413741f), -0.284496736f), 0.254829592f);
  float e = __builtin_amdgcn_exp2f(z * z * -1.4426950408889634f);
  float w = poly * e;
  float r = fmaxf(val, 0.0f);
  return __builtin_fmaf(-0.5f * av, w, r);
}

// 1024-pt complex FFT over LDS ping-pong buffers; result lands back in bufA.
__device__ __forceinline__ void fft1024(float2* bufA, float2* bufB,
                                        const float2* tw, int lt) {
  float2* s = bufA;
  float2* d = bufB;
  for (int m = 1; m < 1024; m <<= 1) {
#pragma unroll
    for (int r2 = 0; r2 < 2; ++r2) {
      int u = lt + r2 * 256;
      int k = u & (m - 1);
      int jm = u - k;
      float2 c0 = s[u];
      float2 c1 = s[u + 512];
      float2 wt = tw[jm];
      float2 su = make_float2(c0.x + c1.x, c0.y + c1.y);
      float2 df = make_float2(c0.x - c1.x, c0.y - c1.y);
      float2 pr = cmul(wt, df);
      d[2 * jm + k] = su;
      d[2 * jm + k + m] = pr;
    }
    __syncthreads();
    float2* tmp = s; s = d; d = tmp;
  }
}

// 512-pt complex FFT (one butterfly per thread per stage); returns result ptr.
__device__ __forceinline__ float2* fft512(float2* bufA, float2* bufB,
                                          const float2* tw, int lt) {
  float2* s = bufA;
  float2* d = bufB;
  for (int m = 1; m < 512; m <<= 1) {
    int u = lt;
    int k = u & (m - 1);
    int jm = u - k;
    float2 c0 = s[u];
    float2 c1 = s[u + 256];
    float2 wt = tw[jm];
    float2 su = make_float2(c0.x + c1.x, c0.y + c1.y);
    float2 df = make_float2(c0.x - c1.x, c0.y - c1.y);
    float2 pr = cmul(wt, df);
    d[2 * jm + k] = su;
    d[2 * jm + k + m] = pr;
    __syncthreads();
    float2* tmp = s; s = d; d = tmp;
  }
  return s;   // 9 stages -> result in bufB
}

// ---------------------------------------------------------------------------
// Weight-row FFT, PACKED-REAL: each complex 1024-FFT carries TWO real rows
// (z = a + i*b; A[k] = 0.5(Z[k]+conj(Z[N-k])), B[k] = -i/2 (Z[k]-conj(Z[N-k]))).
// Block = 2 slots x 2 rows = 4 weight rows.  Grid 768 blocks for 3072 weight
// rows + 1 block for biases (slot 1536: bq+i*bk; slot 1537: bv self-packed).
// ---------------------------------------------------------------------------
__global__ __launch_bounds__(512) void wfft_k(
    const float* __restrict__ Wq, const float* __restrict__ Wk,
    const float* __restrict__ Wv, const float* __restrict__ bq,
    const float* __restrict__ bk, const float* __restrict__ bv,
    float* __restrict__ WfAll, float* __restrict__ biasC) {
  __shared__ float2 tw[512];
  __shared__ float2 bufA[2][1024];
  __shared__ float2 bufB[2][1024];
  const int tid = threadIdx.x;
  const int rh = tid >> 8;          // slot within block: 0/1
  const int lt = tid & 255;
  const int slot = blockIdx.x * 2 + rh;   // 0..1537
  const float *src0, *src1;
  float *dstA, *dstB = nullptr;
  bool storeB = true;
  if (slot < 1536) {
    const int p = slot >> 9;        // 512 slots (1024 rows) per projection
    const int j = slot & 511;
    const float* W = (p == 0) ? Wq : ((p == 1) ? Wk : Wv);
    src0 = W + (size_t)(2 * j) * DD;
    src1 = W + (size_t)(2 * j + 1) * DD;
    dstA = WfAll + ((size_t)p * DD + 2 * j) * WFP;
    dstB = WfAll + ((size_t)p * DD + 2 * j + 1) * WFP;
  } else if (slot == 1536) {
    src0 = bq; src1 = bk;
    dstA = biasC;
    dstB = biasC + WFP;
  } else {
    src0 = bv; src1 = bv;            // self-packed: A-part = rfft(bv) exactly
    dstA = biasC + 2 * (size_t)WFP;
    storeB = false;
  }
  if (rh == 0) {
    for (int t = lt; t < 512; t += 256) {
      float ang = -6.2831853071795864769f * (float)t * (1.0f / 1024.0f);
      tw[t] = make_float2(cosf(ang), sinf(ang));
    }
  }
  for (int t = lt; t < 1024; t += 256)
    bufA[rh][t] = make_float2(src0[t], src1[t]);
  __syncthreads();
  fft1024(bufA[rh], bufB[rh], tw, lt);
  // unpack Hermitian halves
  for (int k = lt; k <= 512; k += 256) {
    const int nk = (1024 - k) & 1023;
    const float2 zk = bufA[rh][k];
    const float2 zn = bufA[rh][nk];
    dstA[2 * k]     = 0.5f * (zk.x + zn.x);
    dstA[2 * k + 1] = 0.5f * (zk.y - zn.y);
    if (storeB) {
      dstB[2 * k]     = 0.5f * (zk.y + zn.y);
      dstB[2 * k + 1] = 0.5f * (zn.x - zk.x);
    }
  }
  for (int j = 1026 + lt; j < WFP; j += 256) {
    dstA[j] = 0.f;
    if (storeB) dstB[j] = 0.f;
  }
}

// ---------------------------------------------------------------------------
// QKV transpose + cast: all 3 projections in one launch (z = projection).
// ---------------------------------------------------------------------------
__global__ __launch_bounds__(256) void transpose_cast_qkv_k(
    const float* __restrict__ WfAll, f16_t* __restrict__ BtH) {
  __shared__ float tile[32][33];
  const int tx = threadIdx.x & 31, ty = threadIdx.x >> 5;  // 32 x 8
  const int n0 = blockIdx.x * 32, k0 = blockIdx.y * 32;
  const int pp = blockIdx.z;
  const float* W = WfAll + (size_t)pp * DD * WFP;
  f16_t* Wt = BtH + (size_t)pp * WFP * DD;
#pragma unroll
  for (int i = 0; i < 32; i += 8)
    tile[ty + i][tx] = W[(size_t)(k0 + ty + i) * WFP + n0 + tx];
  __syncthreads();
#pragma unroll
  for (int i = 0; i < 32; i += 8)
    Wt[(size_t)(n0 + ty + i) * DD + k0 + tx] = (f16_t)tile[tx][ty + i];
}

// MLP transposes: W1 (z=0) and W2 (z=1) in one launch, role-swapped mapping.
__global__ __launch_bounds__(256) void transpose_mlp_k(
    const float* __restrict__ W1, f16_t* __restrict__ W1T,
    const float* __restrict__ W2, f16_t* __restrict__ W2T) {
  __shared__ float tile[32][33];
  const int tx = threadIdx.x & 31, ty = threadIdx.x >> 5;  // 32 x 8
  const float* W; f16_t* Wt; int K, N, n0, k0;
  if (blockIdx.z == 0) {         // W1: K=1024, N=4096; grid x=128 n, y=32 k
    W = W1; Wt = W1T; K = DD; N = NHID;
    n0 = blockIdx.x * 32; k0 = blockIdx.y * 32;
  } else {                       // W2: K=4096, N=1024; x=128 k, y=32 n
    W = W2; Wt = W2T; K = NHID; N = DD;
    n0 = blockIdx.y * 32; k0 = blockIdx.x * 32;
  }
#pragma unroll
  for (int i = 0; i < 32; i += 8)
    tile[ty + i][tx] = W[(size_t)(k0 + ty + i) * N + n0 + tx];
  __syncthreads();
#pragma unroll
  for (int i = 0; i < 32; i += 8)
    Wt[(size_t)(n0 + ty + i) * K + k0 + tx] = (f16_t)tile[tx][ty + i];
}

// ---------------------------------------------------------------------------
// LayerNorm (fp32 in) -> fp16.  One block per row of 1024.
// ---------------------------------------------------------------------------
__global__ __launch_bounds__(256) void ln_cast_k(
    const float* __restrict__ x, const float* __restrict__ g,
    const float* __restrict__ b, f16_t* __restrict__ hH) {
  const int row = blockIdx.x, tid = threadIdx.x;
  __shared__ float red[8];
  const float* xr = x + (size_t)row * DD;
  float v[4], ls = 0.f, lq = 0.f;
#pragma unroll
  for (int i = 0; i < 4; ++i) {
    v[i] = xr[i * 256 + tid];
    ls += v[i];
    lq += v[i] * v[i];
  }
#pragma unroll
  for (int o = 32; o > 0; o >>= 1) {
    ls += __shfl_down(ls, o);
    lq += __shfl_down(lq, o);
  }
  const int lane = tid & 63, w = tid >> 6;
  if (lane == 0) { red[w] = ls; red[w + 4] = lq; }
  __syncthreads();
  const float S = red[0] + red[1] + red[2] + red[3];
  const float Q = red[4] + red[5] + red[6] + red[7];
  const float mean = S * (1.f / 1024.f);
  const float var = Q * (1.f / 1024.f) - mean * mean;
  const float rs = rsqrtf(var + 1e-5f);
#pragma unroll
  for (int i = 0; i < 4; ++i) {
    int n = i * 256 + tid;
    float val = (v[i] - mean) * rs * g[n] + b[n];
    hH[(size_t)row * DD + n] = (f16_t)val;
  }
}

// ---------------------------------------------------------------------------
// QKV GEMM, uniform fp16 in / fp32 out: M=8192, N=3456, K=1024.  128x128
// tile, 32 KB LDS, m97-style staging loop, XCD snake, 1728 blocks, 3/CU.
// ---------------------------------------------------------------------------
__global__ __launch_bounds__(256, 3) void gemm_qkv_k(
    const f16_t* __restrict__ A, const f16_t* __restrict__ Bt,
    const float* __restrict__ bias, float* __restrict__ outF) {
  __shared__ alignas(16) f16_t AsH[128 * 64];
  __shared__ alignas(16) f16_t BsH[128 * 64];
  const int tid = threadIdx.x;
  const int lane = tid & 63;
  const int w = tid >> 6;
  const int wm = w >> 1, wn = w & 1;

  const int lin = blockIdx.x;
  const int s = (lin & 7) * 216 + (lin >> 3);
  const int g = s / 108;
  const int r = s % 108;
  const int n = r >> 2;
  const int m0 = g * 4 + (r & 3);
  const int bn = n * 128;
  const int bm = m0 * 128;

  f32x4 acc[4][4];
#pragma unroll
  for (int i = 0; i < 4; ++i)
#pragma unroll
    for (int j = 0; j < 4; ++j) acc[i][j] = (f32x4){0.f, 0.f, 0.f, 0.f};

  const int srow = lane >> 3;
  const int slot = lane & 7;

  for (int kt = 0; kt < 1024; kt += 64) {
#pragma unroll
    for (int i = 0; i < 4; ++i) {
      const int rb = (i * 4 + w) * 8;
      const int row = rb + srow;
      const int gg = (slot - (row & 7)) & 7;
      size_t ga = (size_t)(bm + row) * 1024 + kt + gg * 8;
      size_t gb = (size_t)(bn + row) * 1024 + kt + gg * 8;
      async_cp16(A + ga, &AsH[rb * 64]);
      async_cp16(Bt + gb, &BsH[rb * 64]);
    }
    __syncthreads();
#pragma unroll
    for (int ks = 0; ks < 2; ++ks) {
      const int cgbase = ks * 4 + (lane >> 4);
      f16x8 ah[4], bh[4];
#pragma unroll
      for (int mt = 0; mt < 4; ++mt) {
        int m = wm * 64 + mt * 16 + (lane & 15);
        int sl = (cgbase + (m & 7)) & 7;
        ah[mt] = *(const f16x8*)(&AsH[m * 64 + sl * 8]);
      }
#pragma unroll
      for (int nt = 0; nt < 4; ++nt) {
        int nn = wn * 64 + nt * 16 + (lane & 15);
        int sl = (cgbase + (nn & 7)) & 7;
        bh[nt] = *(const f16x8*)(&BsH[nn * 64 + sl * 8]);
      }
#pragma unroll
      for (int mt = 0; mt < 4; ++mt)
#pragma unroll
        for (int nt = 0; nt < 4; ++nt)
          acc[mt][nt] = __builtin_amdgcn_mfma_f32_16x16x32_f16(
              ah[mt], bh[nt], acc[mt][nt], 0, 0, 0);
    }
    __syncthreads();
  }

  const int q = lane >> 4;
  const int cn = lane & 15;
#pragma unroll
  for (int mt = 0; mt < 4; ++mt) {
#pragma unroll
    for (int nt = 0; nt < 4; ++nt) {
      const int gcol = bn + wn * 64 + nt * 16 + cn;
      const float bv = bias[gcol];
      const int grow0 = bm + wm * 64 + mt * 16 + q * 4;
#pragma unroll
      for (int i = 0; i < 4; ++i) {
        size_t idx = (size_t)(grow0 + i) * NQKV + gcol;
        outF[idx] = acc[mt][nt][i] + bv;
      }
    }
  }
}

// ---------------------------------------------------------------------------
// 8-phase GEMM building blocks (R4-proven versions).
// ---------------------------------------------------------------------------
template <int RHALF>
__device__ __forceinline__ void stage_half(const f16_t* __restrict__ G,
                                           int grow0, int ldk, int kt,
                                           f16_t* ls, int w, int lane) {
  const int srow = lane >> 3;
  const int slot = lane & 7;
#pragma unroll
  for (int j = 0; j < RHALF / 64; ++j) {
    const int rb = (w + j * 8) * 8;           // row block within half
    const int row = rb + srow;
    const int gg = (slot - (row & 7)) & 7;    // pre-swizzled global col-group
    async_cp16(G + (size_t)(grow0 + row) * ldk + kt + gg * 8, ls + rb * 64);
  }
}

template <int BM, int BN>
__device__ __forceinline__ void readA(const f16_t* As, int mq, int wm, int lane,
                                      f16x8 (&aR)[BM / 64][2]) {
#pragma unroll
  for (int mf = 0; mf < BM / 64; ++mf) {
    const int m = mq * (BM / 2) + wm * (BM / 4) + mf * 16 + (lane & 15);
#pragma unroll
    for (int ks = 0; ks < 2; ++ks) {
      const int cg = ks * 4 + (lane >> 4);
      const int sl = (cg + (m & 7)) & 7;
      aR[mf][ks] = *(const f16x8*)(As + m * 64 + sl * 8);
    }
  }
}

template <int BM, int BN>
__device__ __forceinline__ void readB(const f16_t* Bs, int nq, int wn, int lane,
                                      f16x8 (&bR)[BN / 128][2]) {
#pragma unroll
  for (int nf = 0; nf < BN / 128; ++nf) {
    const int n = nq * (BN / 2) + wn * (BN / 8) + nf * 16 + (lane & 15);
#pragma unroll
    for (int ks = 0; ks < 2; ++ks) {
      const int cg = ks * 4 + (lane >> 4);
      const int sl = (cg + (n & 7)) & 7;
      bR[nf][ks] = *(const f16x8*)(Bs + n * 64 + sl * 8);
    }
  }
}

template <int MF, int NF>
__device__ __forceinline__ void mfma_q(f32x4 (&acc)[MF][NF],
                                       const f16x8 (&aR)[MF][2],
                                       const f16x8 (&bR)[NF][2]) {
#pragma unroll
  for (int ks = 0; ks < 2; ++ks)
#pragma unroll
    for (int mf = 0; mf < MF; ++mf)
#pragma unroll
      for (int nf = 0; nf < NF; ++nf)
        acc[mf][nf] = __builtin_amdgcn_mfma_f32_16x16x32_f16(
            aR[mf][ks], bR[nf][ks], acc[mf][nf], 0, 0, 0);
}

// EPI 1: fast-gelu -> fp16.  EPI 2: +bias+resid -> fp32.  (R4 proven)
template <int BM, int BN, int MM, int NN, int KK, int EPI>
__global__ __launch_bounds__(512, 2) void gemm8p_k(
    const f16_t* __restrict__ A, const f16_t* __restrict__ Bt,
    const float* __restrict__ bias, const float* __restrict__ resid,
    float* __restrict__ outF, f16_t* __restrict__ outH) {
  constexpr int MF = BM / 64;      // M-frags per phase (one strip)
  constexpr int NF = BN / 128;     // N-frags per phase
  constexpr int LA = BM / 128;     // loads/thread per A-half
  constexpr int LB = BN / 128;     // loads/thread per B-half
  constexpr int NT = KK / 64;
  constexpr int TILE = (BM + BN) * 64;
  __shared__ alignas(16) f16_t lds[2 * TILE];

  const int tid = threadIdx.x;
  const int lane = tid & 63;
  const int w = tid >> 6;          // 8 waves
  const int wm = w >> 2;           // 0..1
  const int wn = w & 3;            // 0..3

  constexpr int ntm = MM / BM, ntn = NN / BN;
  constexpr int per = (ntm * ntn) / 8;   // nwg % 8 == 0 for both instantiations
  const int lin = (int)blockIdx.x;
  const int s = (lin & 7) * per + (lin >> 3);
  const int bn = (s % ntn) * BN;
  const int bm = (s / ntn) * BM;

  f32x4 acc[2][2][MF][NF];
#pragma unroll
  for (int a0 = 0; a0 < 2; ++a0)
#pragma unroll
    for (int a1 = 0; a1 < 2; ++a1)
#pragma unroll
      for (int mf = 0; mf < MF; ++mf)
#pragma unroll
        for (int nf = 0; nf < NF; ++nf)
          acc[a0][a1][mf][nf] = (f32x4){0.f, 0.f, 0.f, 0.f};

  // prologue: stage tile 0 in need-order A0,B0,B1,A1; wait for A0,B0.
  {
    f16_t* A0s = lds;
    f16_t* B0s = lds + BM * 64;
    stage_half<BM / 2>(A, bm, KK, 0, A0s, w, lane);
    stage_half<BN / 2>(Bt, bn, KK, 0, B0s, w, lane);
    stage_half<BN / 2>(Bt, bn + BN / 2, KK, 0, B0s + (BN / 2) * 64, w, lane);
    stage_half<BM / 2>(A, bm + BM / 2, KK, 0, A0s + (BM / 2) * 64, w, lane);
  }
  vwait<LA + LB>();
  __builtin_amdgcn_s_barrier();

  f16x8 aR[MF][2], bR0[NF][2], bR1[NF][2];

  for (int t = 0; t < NT; ++t) {
    const int cur = t & 1;
    f16_t* As = lds + cur * TILE;
    f16_t* Bs = As + BM * 64;
    f16_t* Asn = lds + (cur ^ 1) * TILE;
    f16_t* Bsn = Asn + BM * 64;
    const bool pre = (t + 1 < NT);
    const int ktn = (t + 1) << 6;

    // ---- phase 1: Q(0,0) --------------------------------------------------
    readA<BM, BN>(As, 0, wm, lane, aR);
    readB<BM, BN>(Bs, 0, wn, lane, bR0);
    if (pre) stage_half<BM / 2>(A, bm, KK, ktn, Asn, w, lane);
    __builtin_amdgcn_s_barrier();
    __builtin_amdgcn_s_setprio(1);
    mfma_q<MF, NF>(acc[0][0], aR, bR0);
    __builtin_amdgcn_s_setprio(0);
    if (pre) vwait<2 * LA>(); else vwait<LA>();
    __builtin_amdgcn_s_barrier();

    // ---- phase 2: Q(0,1) --------------------------------------------------
    readB<BM, BN>(Bs, 1, wn, lane, bR1);
    if (pre) stage_half<BN / 2>(Bt, bn, KK, ktn, Bsn, w, lane);
    __builtin_amdgcn_s_barrier();
    __builtin_amdgcn_s_setprio(1);
    mfma_q<MF, NF>(acc[0][1], aR, bR1);
    __builtin_amdgcn_s_setprio(0);
    if (pre) vwait<LA + LB>(); else vwait<0>();
    __builtin_amdgcn_s_barrier();

    // ---- phase 3: Q(1,0) --------------------------------------------------
    readA<BM, BN>(As, 1, wm, lane, aR);
    if (pre) stage_half<BN / 2>(Bt, bn + BN / 2, KK, ktn,
                                Bsn + (BN / 2) * 64, w, lane);
    __builtin_amdgcn_s_barrier();
    __builtin_amdgcn_s_setprio(1);
    mfma_q<MF, NF>(acc[1][0], aR, bR0);
    __builtin_amdgcn_s_setprio(0);
    __builtin_amdgcn_s_barrier();              // no vmcnt (ph4 reads nothing)

    // ---- phase 4: Q(1,1) --------------------------------------------------
    if (pre) stage_half<BM / 2>(A, bm + BM / 2, KK, ktn,
                                Asn + (BM / 2) * 64, w, lane);
    __builtin_amdgcn_s_barrier();
    __builtin_amdgcn_s_setprio(1);
    mfma_q<MF, NF>(acc[1][1], aR, bR1);
    __builtin_amdgcn_s_setprio(0);
    if (pre) vwait<LA + LB>();                 // boundary: A0',B0' landed
    __builtin_amdgcn_s_barrier();
  }

  const int q4 = lane >> 4;
  const int cn = lane & 15;
#pragma unroll
  for (int mq = 0; mq < 2; ++mq)
#pragma unroll
    for (int nq = 0; nq < 2; ++nq)
#pragma unroll
      for (int mf = 0; mf < MF; ++mf)
#pragma unroll
        for (int nf = 0; nf < NF; ++nf) {
          const int gcol = bn + nq * (BN / 2) + wn * (BN / 8) + nf * 16 + cn;
          const float bv = bias[gcol];
          const int grow0 = bm + mq * (BM / 2) + wm * (BM / 4) + mf * 16 + q4 * 4;
#pragma unroll
          for (int i = 0; i < 4; ++i) {
            const float val = acc[mq][nq][mf][nf][i] + bv;
            const size_t idx = (size_t)(grow0 + i) * NN + gcol;
            if (EPI == 1) {
              outH[idx] = (f16_t)fast_gelu(val);
            } else {
              outF[idx] = val + resid[idx];
            }
          }
        }
}

// ---------------------------------------------------------------------------
// Inline normalize helpers reading raw fp32 bins from qkv_f rows (1728
// float2 bins: q at [f], k at [576+f], v at [1152+f]).
// ---------------------------------------------------------------------------
__device__ __forceinline__ float2 unitc(float2 a) {
  float inv = 1.0f / fmaxf(sqrtf(a.x * a.x + a.y * a.y), 1e-8f);
  return make_float2(a.x * inv, a.y * inv);
}
__device__ __forceinline__ float2 bind_bin(const float2* r, int f) {
  float2 kn = unitc(r[576 + f]);
  float2 vn = unitc(r[1152 + f]);
  return cmul(kn, vn);
}

// ---------------------------------------------------------------------------
// Fused 3-phase causal prefix sum (cooperative launch, grid.sync between
// phases).  512 blocks x 256 thr, no LDS -> trivially co-resident.
// Phase 1: per-chunk sums -> T.  Phase 2: per-bin Kogge-Stone exclusive scan
// over 64 chunks (one wave per bin).  Phase 3: rescan chunks + write Scum.
// ---------------------------------------------------------------------------
__global__ __launch_bounds__(256) void scan_fused_k(
    const float* __restrict__ qkvF, float2* __restrict__ T,
    float2* __restrict__ Scum) {
  cg::grid_group grid = cg::this_grid();
  const int bid = blockIdx.x;
  const int sc = bid & 63;
  const int fh = (bid >> 6) & 1;
  const int b = bid >> 7;
  const int s0 = sc * SCHUNK;
  const float2* base = (const float2*)(qkvF + ((size_t)(b * SSEQ + s0)) * NQKV);

  // ---- phase 1: chunk sums ----
  for (int f = fh * 256 + threadIdx.x; f < FBINS; f += 512) {
    float2 acc = make_float2(0.f, 0.f);
    const float2* r = base;
    for (int i = 0; i < SCHUNK; ++i) {
      float2 pv = bind_bin(r, f);
      acc.x += pv.x; acc.y += pv.y;
      r += NQKV / 2;
    }
    T[((size_t)b * NCHUNK + sc) * FBINS + f] = acc;
  }
  grid.sync();

  // ---- phase 2: exclusive scan over chunks, one wave per (batch, bin) ----
  {
    const int lane = threadIdx.x & 63;
    const int gw = blockIdx.x * 4 + (threadIdx.x >> 6);   // 0..2047
    for (int bin = gw; bin < NB * FBINS; bin += 2048) {
      const int bb = bin / FBINS, f = bin % FBINS;
      const size_t a = ((size_t)bb * NCHUNK + lane) * FBINS + f;
      float2 v = T[a];
#pragma unroll
      for (int o = 1; o < 64; o <<= 1) {
        float vx = __shfl_up(v.x, o);
        float vy = __shfl_up(v.y, o);
        if (lane >= o) { v.x += vx; v.y += vy; }
      }
      float ex = __shfl_up(v.x, 1);
      float ey = __shfl_up(v.y, 1);
      if (lane == 0) { ex = 0.f; ey = 0.f; }
      T[a] = make_float2(ex, ey);
    }
  }
  grid.sync();

  // ---- phase 3: rescan with offsets, write Scum ----
  for (int f = fh * 256 + threadIdx.x; f < FBINS; f += 512) {
    float2 acc = T[((size_t)b * NCHUNK + sc) * FBINS + f];
    const float2* r = base;
    size_t orow = ((size_t)(b * SSEQ + s0)) * FPAD + f;
    for (int i = 0; i < SCHUNK; ++i) {
      float2 pv = bind_bin(r, f);
      acc.x += pv.x; acc.y += pv.y;
      Scum[orow] = acc;
      r += NQKV / 2;
      orow += FPAD;
    }
  }
}

// ---------------------------------------------------------------------------
// Unbind + LN2, 2 rows per 512-thread block (R4-proven version).
// ---------------------------------------------------------------------------
__global__ __launch_bounds__(512) void unbind_ln2_k(
    const float2* __restrict__ Scum, const float* __restrict__ qkvF,
    const float* __restrict__ x, float* __restrict__ x2out,
    f16_t* __restrict__ h2, const float* __restrict__ g2,
    const float* __restrict__ b2) {
  __shared__ float2 tw[256];     // e^{+2pi i t/512}
  __shared__ float2 Marr[2][513];
  __shared__ float2 bufA[2][512];
  __shared__ float2 bufB[2][512];
  __shared__ float red[2][8];
  const int tid = threadIdx.x;
  const int rh = tid >> 8;       // row half 0/1
  const int lt = tid & 255;
  const int row = blockIdx.x * 2 + rh;

  if (rh == 0) {
    float ang = 6.2831853071795864769f * (float)lt * (1.0f / 512.0f);
    tw[lt] = make_float2(cosf(ang), sinf(ang));
  }
  const float2* qrow = (const float2*)(qkvF + (size_t)row * NQKV);
  for (int t = lt; t <= 512; t += 256) {
    float2 sc = Scum[(size_t)row * FPAD + t];
    float2 fq = unitc(qrow[t]);
    Marr[rh][t] = make_float2(sc.x * fq.x + sc.y * fq.y,
                              sc.y * fq.x - sc.x * fq.y);
  }
  __syncthreads();
  // build Z into bufA
#pragma unroll
  for (int rr = 0; rr < 2; ++rr) {
    int t = lt + rr * 256;
    float2 a = Marr[rh][t];
    float2 b = Marr[rh][512 - t];
    float2 E = make_float2(0.5f * (a.x + b.x), 0.5f * (a.y - b.y));
    float2 Dd = make_float2(0.5f * (a.x - b.x), 0.5f * (a.y + b.y));
    float ang = 6.2831853071795864769f * (float)t * (1.0f / 1024.0f);
    float cw = cosf(ang), sw = sinf(ang);
    float2 O = make_float2(cw * Dd.x - sw * Dd.y, cw * Dd.y + sw * Dd.x);
    bufA[rh][t] = make_float2(E.x - O.y, E.y + O.x);
  }
  __syncthreads();
  float2* res = fft512(bufA[rh], bufB[rh], tw, lt);

  const float* xr = x + (size_t)row * DD;
  float v[2][2];
  float ls = 0.f, lq = 0.f;
#pragma unroll
  for (int rr = 0; rr < 2; ++rr) {
    int n = lt + rr * 256;
    float2 z = res[n];
    float2 xv = *(const float2*)(xr + 2 * n);
    float v0 = xv.x + z.x * (1.0f / 512.0f);
    float v1 = xv.y + z.y * (1.0f / 512.0f);
    *(float2*)(x2out + (size_t)row * DD + 2 * n) = make_float2(v0, v1);
    v[rr][0] = v0; v[rr][1] = v1;
    ls += v0 + v1;
    lq += v0 * v0 + v1 * v1;
  }
#pragma unroll
  for (int o = 32; o > 0; o >>= 1) {
    ls += __shfl_down(ls, o);
    lq += __shfl_down(lq, o);
  }
  const int lane = tid & 63, w4 = (tid >> 6) & 3;
  if (lane == 0) { red[rh][w4] = ls; red[rh][w4 + 4] = lq; }
  __syncthreads();
  const float S = red[rh][0] + red[rh][1] + red[rh][2] + red[rh][3];
  const float Q = red[rh][4] + red[rh][5] + red[rh][6] + red[rh][7];
  const float mean = S * (1.f / 1024.f);
  const float var = Q * (1.f / 1024.f) - mean * mean;
  const float rs = rsqrtf(var + 1e-5f);
  f16_t* hr = h2 + (size_t)row * DD;
#pragma unroll
  for (int rr = 0; rr < 2; ++rr) {
    int n = lt + rr * 256;
    float2 gv = *(const float2*)(g2 + 2 * n);
    float2 bv = *(const float2*)(b2 + 2 * n);
    f16x2 hp;
    hp[0] = (f16_t)((v[rr][0] - mean) * rs * gv.x + bv.x);
    hp[1] = (f16_t)((v[rr][1] - mean) * rs * gv.y + bv.y);
    *(f16x2*)(hr + 2 * n) = hp;
  }
}

// ---------------------------------------------------------------------------
extern "C" void kernel_launch(void* const* d_in, const int* in_sizes, int n_in,
                              void* d_out, int out_size, void* d_ws,
                              size_t ws_size, hipStream_t stream) {
  const float* x     = (const float*)d_in[0];
  const float* Wq    = (const float*)d_in[1];
  const float* bq    = (const float*)d_in[2];
  const float* Wk    = (const float*)d_in[3];
  const float* bk    = (const float*)d_in[4];
  const float* Wv    = (const float*)d_in[5];
  const float* bv    = (const float*)d_in[6];
  const float* ln1_g = (const float*)d_in[7];
  const float* ln1_b = (const float*)d_in[8];
  const float* ln2_g = (const float*)d_in[9];
  const float* ln2_b = (const float*)d_in[10];
  const float* W1    = (const float*)d_in[11];
  const float* b1    = (const float*)d_in[12];
  const float* W2    = (const float*)d_in[13];
  const float* b2    = (const float*)d_in[14];
  float* out = (float*)d_out;

  char* p = (char*)d_ws;
  auto take = [&](size_t bytes) {
    char* r = p;
    p += (bytes + 255) & ~(size_t)255;
    return r;
  };
  f16_t* BtH   = (f16_t*)take((size_t)NQKV * DD * sizeof(f16_t));
  f16_t* W1T   = (f16_t*)take((size_t)NHID * DD * sizeof(f16_t));
  f16_t* W2T   = (f16_t*)take((size_t)DD * NHID * sizeof(f16_t));
  float* biasC = (float*)take((size_t)NQKV * sizeof(float));
  f16_t* hbuf  = (f16_t*)take((size_t)MROWS * DD * sizeof(f16_t));   // h, then h2
  char*  big   = take((size_t)MROWS * NQKV * sizeof(float));         // WfAll, qkvF, mlp1
  float2* Scum = (float2*)take((size_t)MROWS * FPAD * sizeof(float2));
  float* x2    = (float*)take((size_t)MROWS * DD * sizeof(float));
  float2* Tch  = (float2*)take((size_t)NB * NCHUNK * FBINS * sizeof(float2));
  // time-disjoint aliases within big:
  float* WfAll   = (float*)big;                 // prep phase only
  float* qkv_f   = (float*)big;                 // fp32 bins (113 MB)
  f16_t* mlp1    = (f16_t*)big;                 // qkv_f dead before MLP1 writes

  // 1. FFT weight rows (packed-real, 2 rows/FFT) + biases -> WfAll, biasC
  wfft_k<<<769, 512, 0, stream>>>(Wq, Wk, Wv, bq, bk, bv, WfAll, biasC);
  // 2. transpose + cast -> BtH (3456 x 1024)  [single launch, z = projection]
  transpose_cast_qkv_k<<<dim3(WFP / 32, DD / 32, 3), 256, 0, stream>>>(
      WfAll, BtH);
  // 3. MLP weights -> transposed fp16 (W1 and W2 in one launch)
  transpose_mlp_k<<<dim3(128, 32, 2), 256, 0, stream>>>(W1, W1T, W2, W2T);

  // 4. h = LN1(x) -> fp16
  ln_cast_k<<<MROWS, 256, 0, stream>>>(x, ln1_g, ln1_b, hbuf);

  // 5. Fourier bins (fp32): qkv_f = h @ rfft_rows(W)^T + rfft(bias)
  gemm_qkv_k<<<(NQKV / 128) * (MROWS / 128), 256, 0, stream>>>(
      hbuf, BtH, biasC, qkv_f);

  // 6. causal prefix sum over S (fused 3-phase cooperative kernel)
  {
    void* args[] = {(void*)&qkv_f, (void*)&Tch, (void*)&Scum};
    hipLaunchCooperativeKernel((const void*)scan_fused_k,
                               dim3(NB * NCHUNK * 2), dim3(256),
                               args, 0, stream);
  }

  // 7. unbind (packed real iFFT) + residual + LN2   [2 rows/block]
  unbind_ln2_k<<<MROWS / 2, 512, 0, stream>>>(Scum, qkv_f, x, x2, hbuf,
                                              ln2_g, ln2_b);

  // 8. mlp1 = gelu(h2 @ W1 + b1)   [8-phase 256x256, 512 blocks]
  gemm8p_k<256, 256, MROWS, NHID, DD, 1><<<512, 512, 0, stream>>>(
      hbuf, W1T, b1, nullptr, nullptr, mlp1);

  // 9. out = x2 + mlp1 @ W2 + b2  [8-phase 128x256, 256 blocks = 1/CU]
  gemm8p_k<128, 256, MROWS, DD, NHID, 2><<<256, 512, 0, stream>>>(
      mlp1, W2T, b2, x2, out, nullptr);
}

// Round 11
// 477.768 us; speedup vs baseline: 1.2350x; 1.2350x over previous
//
#include <hip/hip_runtime.h>
#include <cstdint>
#include <cstddef>

// Problem constants (B=4, S=2048, D=1024)
#define DD 1024
#define SSEQ 2048
#define NB 4
#define MROWS 8192          // B*S
#define FBINS 513           // rfft bins for N=1024
#define FPAD 520            // padded row stride for Scum buffer
#define WFP 1152            // per-projection padded fp32 column count (9 tiles)
#define NQKV 3456           // 3 * WFP = 27 tiles of 128
#define NHID 4096
#define NCHUNK 128          // scan chunks over S (fine-grained for TLP)
#define SCHUNK 16           // S per chunk

typedef _Float16 f16_t;
typedef _Float16 f16x8 __attribute__((ext_vector_type(8)));
typedef _Float16 f16x2 __attribute__((ext_vector_type(2)));
typedef float f32x4 __attribute__((ext_vector_type(4)));

__device__ __forceinline__ float2 cmul(float2 a, float2 b) {
  return make_float2(a.x * b.x - a.y * b.y, a.x * b.y + a.y * b.x);
}

// Async global->LDS 16B copy (m97: width=16 emits global_load_lds_dwordx4).
__device__ __forceinline__ void async_cp16(const void* g, void* l) {
  __builtin_amdgcn_global_load_lds(
      (const __attribute__((address_space(1))) void*)g,
      (__attribute__((address_space(3))) void*)l, 16, 0, 0);
}

// Counted vmcnt waits (T4): literal immediates via specialization.
template <int N> __device__ __forceinline__ void vwait();
template <> __device__ __forceinline__ void vwait<0>() { asm volatile("s_waitcnt vmcnt(0)" ::: "memory"); }
template <> __device__ __forceinline__ void vwait<1>() { asm volatile("s_waitcnt vmcnt(1)" ::: "memory"); }
template <> __device__ __forceinline__ void vwait<2>() { asm volatile("s_waitcnt vmcnt(2)" ::: "memory"); }
template <> __device__ __forceinline__ void vwait<3>() { asm volatile("s_waitcnt vmcnt(3)" ::: "memory"); }
template <> __device__ __forceinline__ void vwait<4>() { asm volatile("s_waitcnt vmcnt(4)" ::: "memory"); }

// Branchless erf-based gelu, A&S 7.1.26 (|eps_erf| <= 1.5e-7).
__device__ __forceinline__ float fast_gelu(float val) {
  float av = __builtin_fabsf(val);
  float z = av * 0.70710678118654752f;
  float t = __builtin_amdgcn_rcpf(__builtin_fmaf(0.3275911f, z, 1.0f));
  float poly = t * __builtin_fmaf(t,
      __builtin_fmaf(t, __builtin_fmaf(t,
          __builtin_fmaf(t, 1.061405429f, -1.453152027f),
          1.421413741f), -0.284496736f), 0.254829592f);
  float e = __builtin_amdgcn_exp2f(z * z * -1.4426950408889634f);
  float w = poly * e;
  float r = fmaxf(val, 0.0f);
  return __builtin_fmaf(-0.5f * av, w, r);
}

// 1024-pt complex FFT over LDS ping-pong buffers; result lands back in bufA.
__device__ __forceinline__ void fft1024(float2* bufA, float2* bufB,
                                        const float2* tw, int lt) {
  float2* s = bufA;
  float2* d = bufB;
  for (int m = 1; m < 1024; m <<= 1) {
#pragma unroll
    for (int r2 = 0; r2 < 2; ++r2) {
      int u = lt + r2 * 256;
      int k = u & (m - 1);
      int jm = u - k;
      float2 c0 = s[u];
      float2 c1 = s[u + 512];
      float2 wt = tw[jm];
      float2 su = make_float2(c0.x + c1.x, c0.y + c1.y);
      float2 df = make_float2(c0.x - c1.x, c0.y - c1.y);
      float2 pr = cmul(wt, df);
      d[2 * jm + k] = su;
      d[2 * jm + k + m] = pr;
    }
    __syncthreads();
    float2* tmp = s; s = d; d = tmp;
  }
}

// 512-pt complex FFT (one butterfly per thread per stage); returns result ptr.
__device__ __forceinline__ float2* fft512(float2* bufA, float2* bufB,
                                          const float2* tw, int lt) {
  float2* s = bufA;
  float2* d = bufB;
  for (int m = 1; m < 512; m <<= 1) {
    int u = lt;
    int k = u & (m - 1);
    int jm = u - k;
    float2 c0 = s[u];
    float2 c1 = s[u + 256];
    float2 wt = tw[jm];
    float2 su = make_float2(c0.x + c1.x, c0.y + c1.y);
    float2 df = make_float2(c0.x - c1.x, c0.y - c1.y);
    float2 pr = cmul(wt, df);
    d[2 * jm + k] = su;
    d[2 * jm + k + m] = pr;
    __syncthreads();
    float2* tmp = s; s = d; d = tmp;
  }
  return s;   // 9 stages -> result in bufB
}

// ---------------------------------------------------------------------------
// Weight-row FFT, PACKED-REAL (R10-validated): each complex 1024-FFT carries
// TWO real rows.  768 blocks for 3072 weight rows + 1 block for biases.
// ---------------------------------------------------------------------------
__global__ __launch_bounds__(512) void wfft_k(
    const float* __restrict__ Wq, const float* __restrict__ Wk,
    const float* __restrict__ Wv, const float* __restrict__ bq,
    const float* __restrict__ bk, const float* __restrict__ bv,
    float* __restrict__ WfAll, float* __restrict__ biasC) {
  __shared__ float2 tw[512];
  __shared__ float2 bufA[2][1024];
  __shared__ float2 bufB[2][1024];
  const int tid = threadIdx.x;
  const int rh = tid >> 8;          // slot within block: 0/1
  const int lt = tid & 255;
  const int slot = blockIdx.x * 2 + rh;   // 0..1537
  const float *src0, *src1;
  float *dstA, *dstB = nullptr;
  bool storeB = true;
  if (slot < 1536) {
    const int p = slot >> 9;        // 512 slots (1024 rows) per projection
    const int j = slot & 511;
    const float* W = (p == 0) ? Wq : ((p == 1) ? Wk : Wv);
    src0 = W + (size_t)(2 * j) * DD;
    src1 = W + (size_t)(2 * j + 1) * DD;
    dstA = WfAll + ((size_t)p * DD + 2 * j) * WFP;
    dstB = WfAll + ((size_t)p * DD + 2 * j + 1) * WFP;
  } else if (slot == 1536) {
    src0 = bq; src1 = bk;
    dstA = biasC;
    dstB = biasC + WFP;
  } else {
    src0 = bv; src1 = bv;            // self-packed: A-part = rfft(bv) exactly
    dstA = biasC + 2 * (size_t)WFP;
    storeB = false;
  }
  if (rh == 0) {
    for (int t = lt; t < 512; t += 256) {
      float ang = -6.2831853071795864769f * (float)t * (1.0f / 1024.0f);
      tw[t] = make_float2(cosf(ang), sinf(ang));
    }
  }
  for (int t = lt; t < 1024; t += 256)
    bufA[rh][t] = make_float2(src0[t], src1[t]);
  __syncthreads();
  fft1024(bufA[rh], bufB[rh], tw, lt);
  // unpack Hermitian halves
  for (int k = lt; k <= 512; k += 256) {
    const int nk = (1024 - k) & 1023;
    const float2 zk = bufA[rh][k];
    const float2 zn = bufA[rh][nk];
    dstA[2 * k]     = 0.5f * (zk.x + zn.x);
    dstA[2 * k + 1] = 0.5f * (zk.y - zn.y);
    if (storeB) {
      dstB[2 * k]     = 0.5f * (zk.y + zn.y);
      dstB[2 * k + 1] = 0.5f * (zn.x - zk.x);
    }
  }
  for (int j = 1026 + lt; j < WFP; j += 256) {
    dstA[j] = 0.f;
    if (storeB) dstB[j] = 0.f;
  }
}

// ---------------------------------------------------------------------------
// QKV transpose + cast: all 3 projections in one launch (z = projection).
// ---------------------------------------------------------------------------
__global__ __launch_bounds__(256) void transpose_cast_qkv_k(
    const float* __restrict__ WfAll, f16_t* __restrict__ BtH) {
  __shared__ float tile[32][33];
  const int tx = threadIdx.x & 31, ty = threadIdx.x >> 5;  // 32 x 8
  const int n0 = blockIdx.x * 32, k0 = blockIdx.y * 32;
  const int pp = blockIdx.z;
  const float* W = WfAll + (size_t)pp * DD * WFP;
  f16_t* Wt = BtH + (size_t)pp * WFP * DD;
#pragma unroll
  for (int i = 0; i < 32; i += 8)
    tile[ty + i][tx] = W[(size_t)(k0 + ty + i) * WFP + n0 + tx];
  __syncthreads();
#pragma unroll
  for (int i = 0; i < 32; i += 8)
    Wt[(size_t)(n0 + ty + i) * DD + k0 + tx] = (f16_t)tile[tx][ty + i];
}

// MLP transposes: W1 (z=0) and W2 (z=1) in one launch, role-swapped mapping.
__global__ __launch_bounds__(256) void transpose_mlp_k(
    const float* __restrict__ W1, f16_t* __restrict__ W1T,
    const float* __restrict__ W2, f16_t* __restrict__ W2T) {
  __shared__ float tile[32][33];
  const int tx = threadIdx.x & 31, ty = threadIdx.x >> 5;  // 32 x 8
  const float* W; f16_t* Wt; int K, N, n0, k0;
  if (blockIdx.z == 0) {         // W1: K=1024, N=4096; grid x=128 n, y=32 k
    W = W1; Wt = W1T; K = DD; N = NHID;
    n0 = blockIdx.x * 32; k0 = blockIdx.y * 32;
  } else {                       // W2: K=4096, N=1024; x=128 k, y=32 n
    W = W2; Wt = W2T; K = NHID; N = DD;
    n0 = blockIdx.y * 32; k0 = blockIdx.x * 32;
  }
#pragma unroll
  for (int i = 0; i < 32; i += 8)
    tile[ty + i][tx] = W[(size_t)(k0 + ty + i) * N + n0 + tx];
  __syncthreads();
#pragma unroll
  for (int i = 0; i < 32; i += 8)
    Wt[(size_t)(n0 + ty + i) * K + k0 + tx] = (f16_t)tile[tx][ty + i];
}

// ---------------------------------------------------------------------------
// LayerNorm (fp32 in) -> fp16.  One block per row of 1024.
// ---------------------------------------------------------------------------
__global__ __launch_bounds__(256) void ln_cast_k(
    const float* __restrict__ x, const float* __restrict__ g,
    const float* __restrict__ b, f16_t* __restrict__ hH) {
  const int row = blockIdx.x, tid = threadIdx.x;
  __shared__ float red[8];
  const float* xr = x + (size_t)row * DD;
  float v[4], ls = 0.f, lq = 0.f;
#pragma unroll
  for (int i = 0; i < 4; ++i) {
    v[i] = xr[i * 256 + tid];
    ls += v[i];
    lq += v[i] * v[i];
  }
#pragma unroll
  for (int o = 32; o > 0; o >>= 1) {
    ls += __shfl_down(ls, o);
    lq += __shfl_down(lq, o);
  }
  const int lane = tid & 63, w = tid >> 6;
  if (lane == 0) { red[w] = ls; red[w + 4] = lq; }
  __syncthreads();
  const float S = red[0] + red[1] + red[2] + red[3];
  const float Q = red[4] + red[5] + red[6] + red[7];
  const float mean = S * (1.f / 1024.f);
  const float var = Q * (1.f / 1024.f) - mean * mean;
  const float rs = rsqrtf(var + 1e-5f);
#pragma unroll
  for (int i = 0; i < 4; ++i) {
    int n = i * 256 + tid;
    float val = (v[i] - mean) * rs * g[n] + b[n];
    hH[(size_t)row * DD + n] = (f16_t)val;
  }
}

// ---------------------------------------------------------------------------
// QKV GEMM, uniform fp16 in / fp32 out: M=8192, N=3456, K=1024.  128x128
// tile, 32 KB LDS, m97-style staging loop, XCD snake, 1728 blocks, 3/CU.
// ---------------------------------------------------------------------------
__global__ __launch_bounds__(256, 3) void gemm_qkv_k(
    const f16_t* __restrict__ A, const f16_t* __restrict__ Bt,
    const float* __restrict__ bias, float* __restrict__ outF) {
  __shared__ alignas(16) f16_t AsH[128 * 64];
  __shared__ alignas(16) f16_t BsH[128 * 64];
  const int tid = threadIdx.x;
  const int lane = tid & 63;
  const int w = tid >> 6;
  const int wm = w >> 1, wn = w & 1;

  const int lin = blockIdx.x;
  const int s = (lin & 7) * 216 + (lin >> 3);
  const int g = s / 108;
  const int r = s % 108;
  const int n = r >> 2;
  const int m0 = g * 4 + (r & 3);
  const int bn = n * 128;
  const int bm = m0 * 128;

  f32x4 acc[4][4];
#pragma unroll
  for (int i = 0; i < 4; ++i)
#pragma unroll
    for (int j = 0; j < 4; ++j) acc[i][j] = (f32x4){0.f, 0.f, 0.f, 0.f};

  const int srow = lane >> 3;
  const int slot = lane & 7;

  for (int kt = 0; kt < 1024; kt += 64) {
#pragma unroll
    for (int i = 0; i < 4; ++i) {
      const int rb = (i * 4 + w) * 8;
      const int row = rb + srow;
      const int gg = (slot - (row & 7)) & 7;
      size_t ga = (size_t)(bm + row) * 1024 + kt + gg * 8;
      size_t gb = (size_t)(bn + row) * 1024 + kt + gg * 8;
      async_cp16(A + ga, &AsH[rb * 64]);
      async_cp16(Bt + gb, &BsH[rb * 64]);
    }
    __syncthreads();
#pragma unroll
    for (int ks = 0; ks < 2; ++ks) {
      const int cgbase = ks * 4 + (lane >> 4);
      f16x8 ah[4], bh[4];
#pragma unroll
      for (int mt = 0; mt < 4; ++mt) {
        int m = wm * 64 + mt * 16 + (lane & 15);
        int sl = (cgbase + (m & 7)) & 7;
        ah[mt] = *(const f16x8*)(&AsH[m * 64 + sl * 8]);
      }
#pragma unroll
      for (int nt = 0; nt < 4; ++nt) {
        int nn = wn * 64 + nt * 16 + (lane & 15);
        int sl = (cgbase + (nn & 7)) & 7;
        bh[nt] = *(const f16x8*)(&BsH[nn * 64 + sl * 8]);
      }
#pragma unroll
      for (int mt = 0; mt < 4; ++mt)
#pragma unroll
        for (int nt = 0; nt < 4; ++nt)
          acc[mt][nt] = __builtin_amdgcn_mfma_f32_16x16x32_f16(
              ah[mt], bh[nt], acc[mt][nt], 0, 0, 0);
    }
    __syncthreads();
  }

  const int q = lane >> 4;
  const int cn = lane & 15;
#pragma unroll
  for (int mt = 0; mt < 4; ++mt) {
#pragma unroll
    for (int nt = 0; nt < 4; ++nt) {
      const int gcol = bn + wn * 64 + nt * 16 + cn;
      const float bv = bias[gcol];
      const int grow0 = bm + wm * 64 + mt * 16 + q * 4;
#pragma unroll
      for (int i = 0; i < 4; ++i) {
        size_t idx = (size_t)(grow0 + i) * NQKV + gcol;
        outF[idx] = acc[mt][nt][i] + bv;
      }
    }
  }
}

// ---------------------------------------------------------------------------
// 8-phase GEMM building blocks (R4-proven versions).
// ---------------------------------------------------------------------------
template <int RHALF>
__device__ __forceinline__ void stage_half(const f16_t* __restrict__ G,
                                           int grow0, int ldk, int kt,
                                           f16_t* ls, int w, int lane) {
  const int srow = lane >> 3;
  const int slot = lane & 7;
#pragma unroll
  for (int j = 0; j < RHALF / 64; ++j) {
    const int rb = (w + j * 8) * 8;           // row block within half
    const int row = rb + srow;
    const int gg = (slot - (row & 7)) & 7;    // pre-swizzled global col-group
    async_cp16(G + (size_t)(grow0 + row) * ldk + kt + gg * 8, ls + rb * 64);
  }
}

template <int BM, int BN>
__device__ __forceinline__ void readA(const f16_t* As, int mq, int wm, int lane,
                                      f16x8 (&aR)[BM / 64][2]) {
#pragma unroll
  for (int mf = 0; mf < BM / 64; ++mf) {
    const int m = mq * (BM / 2) + wm * (BM / 4) + mf * 16 + (lane & 15);
#pragma unroll
    for (int ks = 0; ks < 2; ++ks) {
      const int cg = ks * 4 + (lane >> 4);
      const int sl = (cg + (m & 7)) & 7;
      aR[mf][ks] = *(const f16x8*)(As + m * 64 + sl * 8);
    }
  }
}

template <int BM, int BN>
__device__ __forceinline__ void readB(const f16_t* Bs, int nq, int wn, int lane,
                                      f16x8 (&bR)[BN / 128][2]) {
#pragma unroll
  for (int nf = 0; nf < BN / 128; ++nf) {
    const int n = nq * (BN / 2) + wn * (BN / 8) + nf * 16 + (lane & 15);
#pragma unroll
    for (int ks = 0; ks < 2; ++ks) {
      const int cg = ks * 4 + (lane >> 4);
      const int sl = (cg + (n & 7)) & 7;
      bR[nf][ks] = *(const f16x8*)(Bs + n * 64 + sl * 8);
    }
  }
}

template <int MF, int NF>
__device__ __forceinline__ void mfma_q(f32x4 (&acc)[MF][NF],
                                       const f16x8 (&aR)[MF][2],
                                       const f16x8 (&bR)[NF][2]) {
#pragma unroll
  for (int ks = 0; ks < 2; ++ks)
#pragma unroll
    for (int mf = 0; mf < MF; ++mf)
#pragma unroll
      for (int nf = 0; nf < NF; ++nf)
        acc[mf][nf] = __builtin_amdgcn_mfma_f32_16x16x32_f16(
            aR[mf][ks], bR[nf][ks], acc[mf][nf], 0, 0, 0);
}

// EPI 1: fast-gelu -> fp16.  EPI 2: +bias+resid -> fp32.  (R4 proven)
template <int BM, int BN, int MM, int NN, int KK, int EPI>
__global__ __launch_bounds__(512, 2) void gemm8p_k(
    const f16_t* __restrict__ A, const f16_t* __restrict__ Bt,
    const float* __restrict__ bias, const float* __restrict__ resid,
    float* __restrict__ outF, f16_t* __restrict__ outH) {
  constexpr int MF = BM / 64;      // M-frags per phase (one strip)
  constexpr int NF = BN / 128;     // N-frags per phase
  constexpr int LA = BM / 128;     // loads/thread per A-half
  constexpr int LB = BN / 128;     // loads/thread per B-half
  constexpr int NT = KK / 64;
  constexpr int TILE = (BM + BN) * 64;
  __shared__ alignas(16) f16_t lds[2 * TILE];

  const int tid = threadIdx.x;
  const int lane = tid & 63;
  const int w = tid >> 6;          // 8 waves
  const int wm = w >> 2;           // 0..1
  const int wn = w & 3;            // 0..3

  constexpr int ntm = MM / BM, ntn = NN / BN;
  constexpr int per = (ntm * ntn) / 8;   // nwg % 8 == 0 for both instantiations
  const int lin = (int)blockIdx.x;
  const int s = (lin & 7) * per + (lin >> 3);
  const int bn = (s % ntn) * BN;
  const int bm = (s / ntn) * BM;

  f32x4 acc[2][2][MF][NF];
#pragma unroll
  for (int a0 = 0; a0 < 2; ++a0)
#pragma unroll
    for (int a1 = 0; a1 < 2; ++a1)
#pragma unroll
      for (int mf = 0; mf < MF; ++mf)
#pragma unroll
        for (int nf = 0; nf < NF; ++nf)
          acc[a0][a1][mf][nf] = (f32x4){0.f, 0.f, 0.f, 0.f};

  // prologue: stage tile 0 in need-order A0,B0,B1,A1; wait for A0,B0.
  {
    f16_t* A0s = lds;
    f16_t* B0s = lds + BM * 64;
    stage_half<BM / 2>(A, bm, KK, 0, A0s, w, lane);
    stage_half<BN / 2>(Bt, bn, KK, 0, B0s, w, lane);
    stage_half<BN / 2>(Bt, bn + BN / 2, KK, 0, B0s + (BN / 2) * 64, w, lane);
    stage_half<BM / 2>(A, bm + BM / 2, KK, 0, A0s + (BM / 2) * 64, w, lane);
  }
  vwait<LA + LB>();
  __builtin_amdgcn_s_barrier();

  f16x8 aR[MF][2], bR0[NF][2], bR1[NF][2];

  for (int t = 0; t < NT; ++t) {
    const int cur = t & 1;
    f16_t* As = lds + cur * TILE;
    f16_t* Bs = As + BM * 64;
    f16_t* Asn = lds + (cur ^ 1) * TILE;
    f16_t* Bsn = Asn + BM * 64;
    const bool pre = (t + 1 < NT);
    const int ktn = (t + 1) << 6;

    // ---- phase 1: Q(0,0) --------------------------------------------------
    readA<BM, BN>(As, 0, wm, lane, aR);
    readB<BM, BN>(Bs, 0, wn, lane, bR0);
    if (pre) stage_half<BM / 2>(A, bm, KK, ktn, Asn, w, lane);
    __builtin_amdgcn_s_barrier();
    __builtin_amdgcn_s_setprio(1);
    mfma_q<MF, NF>(acc[0][0], aR, bR0);
    __builtin_amdgcn_s_setprio(0);
    if (pre) vwait<2 * LA>(); else vwait<LA>();
    __builtin_amdgcn_s_barrier();

    // ---- phase 2: Q(0,1) --------------------------------------------------
    readB<BM, BN>(Bs, 1, wn, lane, bR1);
    if (pre) stage_half<BN / 2>(Bt, bn, KK, ktn, Bsn, w, lane);
    __builtin_amdgcn_s_barrier();
    __builtin_amdgcn_s_setprio(1);
    mfma_q<MF, NF>(acc[0][1], aR, bR1);
    __builtin_amdgcn_s_setprio(0);
    if (pre) vwait<LA + LB>(); else vwait<0>();
    __builtin_amdgcn_s_barrier();

    // ---- phase 3: Q(1,0) --------------------------------------------------
    readA<BM, BN>(As, 1, wm, lane, aR);
    if (pre) stage_half<BN / 2>(Bt, bn + BN / 2, KK, ktn,
                                Bsn + (BN / 2) * 64, w, lane);
    __builtin_amdgcn_s_barrier();
    __builtin_amdgcn_s_setprio(1);
    mfma_q<MF, NF>(acc[1][0], aR, bR0);
    __builtin_amdgcn_s_setprio(0);
    __builtin_amdgcn_s_barrier();              // no vmcnt (ph4 reads nothing)

    // ---- phase 4: Q(1,1) --------------------------------------------------
    if (pre) stage_half<BM / 2>(A, bm + BM / 2, KK, ktn,
                                Asn + (BM / 2) * 64, w, lane);
    __builtin_amdgcn_s_barrier();
    __builtin_amdgcn_s_setprio(1);
    mfma_q<MF, NF>(acc[1][1], aR, bR1);
    __builtin_amdgcn_s_setprio(0);
    if (pre) vwait<LA + LB>();                 // boundary: A0',B0' landed
    __builtin_amdgcn_s_barrier();
  }

  const int q4 = lane >> 4;
  const int cn = lane & 15;
#pragma unroll
  for (int mq = 0; mq < 2; ++mq)
#pragma unroll
    for (int nq = 0; nq < 2; ++nq)
#pragma unroll
      for (int mf = 0; mf < MF; ++mf)
#pragma unroll
        for (int nf = 0; nf < NF; ++nf) {
          const int gcol = bn + nq * (BN / 2) + wn * (BN / 8) + nf * 16 + cn;
          const float bv = bias[gcol];
          const int grow0 = bm + mq * (BM / 2) + wm * (BM / 4) + mf * 16 + q4 * 4;
#pragma unroll
          for (int i = 0; i < 4; ++i) {
            const float val = acc[mq][nq][mf][nf][i] + bv;
            const size_t idx = (size_t)(grow0 + i) * NN + gcol;
            if (EPI == 1) {
              outH[idx] = (f16_t)fast_gelu(val);
            } else {
              outF[idx] = val + resid[idx];
            }
          }
        }
}

// ---------------------------------------------------------------------------
// Inline normalize helpers reading raw fp32 bins from qkv_f rows (1728
// float2 bins: q at [f], k at [576+f], v at [1152+f]).
// ---------------------------------------------------------------------------
__device__ __forceinline__ float2 unitc(float2 a) {
  float inv = 1.0f / fmaxf(sqrtf(a.x * a.x + a.y * a.y), 1e-8f);
  return make_float2(a.x * inv, a.y * inv);
}
__device__ __forceinline__ float2 bind_bin(const float2* r, int f) {
  float2 kn = unitc(r[576 + f]);
  float2 vn = unitc(r[1152 + f]);
  return cmul(kn, vn);
}

// ---------------------------------------------------------------------------
// 3-pass parallel prefix sum over S per (batch, bin).  Fine chunks
// (NCHUNK=128, SCHUNK=16) double the wave count (1024 blocks -> 4096 waves,
// 50% occupancy) and halve each thread's serial chain -- the R10 counters
// showed this phase latency-bound at 21% occupancy / 11% VALU / 8% HBM.
// ---------------------------------------------------------------------------
__global__ __launch_bounds__(256) void scan_pass1_k(
    const float* __restrict__ qkvF, float2* __restrict__ T) {
  const int bid = blockIdx.x;
  const int sc = bid & (NCHUNK - 1);
  const int fh = (bid >> 7) & 1;
  const int b = bid >> 8;
  const int s0 = sc * SCHUNK;
  const float2* base = (const float2*)(qkvF + ((size_t)(b * SSEQ + s0)) * NQKV);
  for (int f = fh * 256 + threadIdx.x; f < FBINS; f += 512) {
    float2 acc = make_float2(0.f, 0.f);
    const float2* r = base;
    for (int i = 0; i < SCHUNK; ++i) {
      float2 pv = bind_bin(r, f);
      acc.x += pv.x; acc.y += pv.y;
      r += NQKV / 2;
    }
    T[((size_t)b * NCHUNK + sc) * FBINS + f] = acc;
  }
}

// One wave per (batch, bin); lane l owns chunk pair (2l, 2l+1).
__global__ __launch_bounds__(256) void scan_pass2_k(float2* __restrict__ T) {
  const int wv = threadIdx.x >> 6, lane = threadIdx.x & 63;
  const int bin = blockIdx.x * 4 + wv;      // 0..2051 == NB*FBINS-1 exactly
  const int b = bin / FBINS, f = bin % FBINS;
  const size_t a0 = ((size_t)b * NCHUNK + 2 * lane) * FBINS + f;
  const size_t a1 = ((size_t)b * NCHUNK + 2 * lane + 1) * FBINS + f;
  float2 c0 = T[a0];
  float2 c1 = T[a1];
  float2 v = make_float2(c0.x + c1.x, c0.y + c1.y);
  // Kogge-Stone inclusive scan of pair-sums across 64 lanes
#pragma unroll
  for (int o = 1; o < 64; o <<= 1) {
    float vx = __shfl_up(v.x, o);
    float vy = __shfl_up(v.y, o);
    if (lane >= o) { v.x += vx; v.y += vy; }
  }
  // exclusive pair offset
  float ex = __shfl_up(v.x, 1);
  float ey = __shfl_up(v.y, 1);
  if (lane == 0) { ex = 0.f; ey = 0.f; }
  T[a0] = make_float2(ex, ey);
  T[a1] = make_float2(ex + c0.x, ey + c0.y);
}

__global__ __launch_bounds__(256) void scan_pass3_k(
    const float* __restrict__ qkvF, const float2* __restrict__ T,
    float2* __restrict__ Scum) {
  const int bid = blockIdx.x;
  const int sc = bid & (NCHUNK - 1);
  const int fh = (bid >> 7) & 1;
  const int b = bid >> 8;
  const int s0 = sc * SCHUNK;
  const float2* base = (const float2*)(qkvF + ((size_t)(b * SSEQ + s0)) * NQKV);
  for (int f = fh * 256 + threadIdx.x; f < FBINS; f += 512) {
    float2 acc = T[((size_t)b * NCHUNK + sc) * FBINS + f];
    const float2* r = base;
    size_t orow = ((size_t)(b * SSEQ + s0)) * FPAD + f;
    for (int i = 0; i < SCHUNK; ++i) {
      float2 pv = bind_bin(r, f);
      acc.x += pv.x; acc.y += pv.y;
      Scum[orow] = acc;
      r += NQKV / 2;
      orow += FPAD;
    }
  }
}

// ---------------------------------------------------------------------------
// Unbind + LN2, 2 rows per 512-thread block (R4-proven version).
// ---------------------------------------------------------------------------
__global__ __launch_bounds__(512) void unbind_ln2_k(
    const float2* __restrict__ Scum, const float* __restrict__ qkvF,
    const float* __restrict__ x, float* __restrict__ x2out,
    f16_t* __restrict__ h2, const float* __restrict__ g2,
    const float* __restrict__ b2) {
  __shared__ float2 tw[256];     // e^{+2pi i t/512}
  __shared__ float2 Marr[2][513];
  __shared__ float2 bufA[2][512];
  __shared__ float2 bufB[2][512];
  __shared__ float red[2][8];
  const int tid = threadIdx.x;
  const int rh = tid >> 8;       // row half 0/1
  const int lt = tid & 255;
  const int row = blockIdx.x * 2 + rh;

  if (rh == 0) {
    float ang = 6.2831853071795864769f * (float)lt * (1.0f / 512.0f);
    tw[lt] = make_float2(cosf(ang), sinf(ang));
  }
  const float2* qrow = (const float2*)(qkvF + (size_t)row * NQKV);
  for (int t = lt; t <= 512; t += 256) {
    float2 sc = Scum[(size_t)row * FPAD + t];
    float2 fq = unitc(qrow[t]);
    Marr[rh][t] = make_float2(sc.x * fq.x + sc.y * fq.y,
                              sc.y * fq.x - sc.x * fq.y);
  }
  __syncthreads();
  // build Z into bufA
#pragma unroll
  for (int rr = 0; rr < 2; ++rr) {
    int t = lt + rr * 256;
    float2 a = Marr[rh][t];
    float2 b = Marr[rh][512 - t];
    float2 E = make_float2(0.5f * (a.x + b.x), 0.5f * (a.y - b.y));
    float2 Dd = make_float2(0.5f * (a.x - b.x), 0.5f * (a.y + b.y));
    float ang = 6.2831853071795864769f * (float)t * (1.0f / 1024.0f);
    float cw = cosf(ang), sw = sinf(ang);
    float2 O = make_float2(cw * Dd.x - sw * Dd.y, cw * Dd.y + sw * Dd.x);
    bufA[rh][t] = make_float2(E.x - O.y, E.y + O.x);
  }
  __syncthreads();
  float2* res = fft512(bufA[rh], bufB[rh], tw, lt);

  const float* xr = x + (size_t)row * DD;
  float v[2][2];
  float ls = 0.f, lq = 0.f;
#pragma unroll
  for (int rr = 0; rr < 2; ++rr) {
    int n = lt + rr * 256;
    float2 z = res[n];
    float2 xv = *(const float2*)(xr + 2 * n);
    float v0 = xv.x + z.x * (1.0f / 512.0f);
    float v1 = xv.y + z.y * (1.0f / 512.0f);
    *(float2*)(x2out + (size_t)row * DD + 2 * n) = make_float2(v0, v1);
    v[rr][0] = v0; v[rr][1] = v1;
    ls += v0 + v1;
    lq += v0 * v0 + v1 * v1;
  }
#pragma unroll
  for (int o = 32; o > 0; o >>= 1) {
    ls += __shfl_down(ls, o);
    lq += __shfl_down(lq, o);
  }
  const int lane = tid & 63, w4 = (tid >> 6) & 3;
  if (lane == 0) { red[rh][w4] = ls; red[rh][w4 + 4] = lq; }
  __syncthreads();
  const float S = red[rh][0] + red[rh][1] + red[rh][2] + red[rh][3];
  const float Q = red[rh][4] + red[rh][5] + red[rh][6] + red[rh][7];
  const float mean = S * (1.f / 1024.f);
  const float var = Q * (1.f / 1024.f) - mean * mean;
  const float rs = rsqrtf(var + 1e-5f);
  f16_t* hr = h2 + (size_t)row * DD;
#pragma unroll
  for (int rr = 0; rr < 2; ++rr) {
    int n = lt + rr * 256;
    float2 gv = *(const float2*)(g2 + 2 * n);
    float2 bv = *(const float2*)(b2 + 2 * n);
    f16x2 hp;
    hp[0] = (f16_t)((v[rr][0] - mean) * rs * gv.x + bv.x);
    hp[1] = (f16_t)((v[rr][1] - mean) * rs * gv.y + bv.y);
    *(f16x2*)(hr + 2 * n) = hp;
  }
}

// ---------------------------------------------------------------------------
extern "C" void kernel_launch(void* const* d_in, const int* in_sizes, int n_in,
                              void* d_out, int out_size, void* d_ws,
                              size_t ws_size, hipStream_t stream) {
  const float* x     = (const float*)d_in[0];
  const float* Wq    = (const float*)d_in[1];
  const float* bq    = (const float*)d_in[2];
  const float* Wk    = (const float*)d_in[3];
  const float* bk    = (const float*)d_in[4];
  const float* Wv    = (const float*)d_in[5];
  const float* bv    = (const float*)d_in[6];
  const float* ln1_g = (const float*)d_in[7];
  const float* ln1_b = (const float*)d_in[8];
  const float* ln2_g = (const float*)d_in[9];
  const float* ln2_b = (const float*)d_in[10];
  const float* W1    = (const float*)d_in[11];
  const float* b1    = (const float*)d_in[12];
  const float* W2    = (const float*)d_in[13];
  const float* b2    = (const float*)d_in[14];
  float* out = (float*)d_out;

  char* p = (char*)d_ws;
  auto take = [&](size_t bytes) {
    char* r = p;
    p += (bytes + 255) & ~(size_t)255;
    return r;
  };
  f16_t* BtH   = (f16_t*)take((size_t)NQKV * DD * sizeof(f16_t));
  f16_t* W1T   = (f16_t*)take((size_t)NHID * DD * sizeof(f16_t));
  f16_t* W2T   = (f16_t*)take((size_t)DD * NHID * sizeof(f16_t));
  float* biasC = (float*)take((size_t)NQKV * sizeof(float));
  f16_t* hbuf  = (f16_t*)take((size_t)MROWS * DD * sizeof(f16_t));   // h, then h2
  char*  big   = take((size_t)MROWS * NQKV * sizeof(float));         // WfAll, qkvF, mlp1
  float2* Scum = (float2*)take((size_t)MROWS * FPAD * sizeof(float2));
  float* x2    = (float*)take((size_t)MROWS * DD * sizeof(float));
  float2* Tch  = (float2*)take((size_t)NB * NCHUNK * FBINS * sizeof(float2));
  // time-disjoint aliases within big:
  float* WfAll   = (float*)big;                 // prep phase only
  float* qkv_f   = (float*)big;                 // fp32 bins (113 MB)
  f16_t* mlp1    = (f16_t*)big;                 // qkv_f dead before MLP1 writes

  // 1. FFT weight rows (packed-real, 2 rows/FFT) + biases -> WfAll, biasC
  wfft_k<<<769, 512, 0, stream>>>(Wq, Wk, Wv, bq, bk, bv, WfAll, biasC);
  // 2. transpose + cast -> BtH (3456 x 1024)  [single launch, z = projection]
  transpose_cast_qkv_k<<<dim3(WFP / 32, DD / 32, 3), 256, 0, stream>>>(
      WfAll, BtH);
  // 3. MLP weights -> transposed fp16 (W1 and W2 in one launch)
  transpose_mlp_k<<<dim3(128, 32, 2), 256, 0, stream>>>(W1, W1T, W2, W2T);

  // 4. h = LN1(x) -> fp16
  ln_cast_k<<<MROWS, 256, 0, stream>>>(x, ln1_g, ln1_b, hbuf);

  // 5. Fourier bins (fp32): qkv_f = h @ rfft_rows(W)^T + rfft(bias)
  gemm_qkv_k<<<(NQKV / 128) * (MROWS / 128), 256, 0, stream>>>(
      hbuf, BtH, biasC, qkv_f);

  // 6. causal prefix sum over S (fine chunks: 1024-block grids, 16-deep
  //    serial chains; pass2 = one wave per bin over 128 chunks)
  scan_pass1_k<<<NB * NCHUNK * 2, 256, 0, stream>>>(qkv_f, Tch);
  scan_pass2_k<<<(NB * FBINS) / 4, 256, 0, stream>>>(Tch);
  scan_pass3_k<<<NB * NCHUNK * 2, 256, 0, stream>>>(qkv_f, Tch, Scum);

  // 7. unbind (packed real iFFT) + residual + LN2   [2 rows/block]
  unbind_ln2_k<<<MROWS / 2, 512, 0, stream>>>(Scum, qkv_f, x, x2, hbuf,
                                              ln2_g, ln2_b);

  // 8. mlp1 = gelu(h2 @ W1 + b1)   [8-phase 256x256, 512 blocks]
  gemm8p_k<256, 256, MROWS, NHID, DD, 1><<<512, 512, 0, stream>>>(
      hbuf, W1T, b1, nullptr, nullptr, mlp1);

  // 9. out = x2 + mlp1 @ W2 + b2  [8-phase 128x256, 256 blocks = 1/CU]
  gemm8p_k<128, 256, MROWS, DD, NHID, 2><<<256, 512, 0, stream>>>(
      mlp1, W2T, b2, x2, out, nullptr);
}

// Round 12
// 448.821 us; speedup vs baseline: 1.3147x; 1.0645x over previous
//
#include <hip/hip_runtime.h>
#include <cstdint>
#include <cstddef>

// Problem constants (B=4, S=2048, D=1024)
#define DD 1024
#define SSEQ 2048
#define NB 4
#define MROWS 8192          // B*S
#define FBINS 513           // rfft bins for N=1024
#define FPAD 520            // padded row stride for Scum buffer
#define WFP 1152            // per-projection padded fp32 column count (9 tiles)
#define NQKV 3456           // 3 * WFP = 27 tiles of 128
#define NHID 4096
#define NCHUNK 128          // scan chunks over S (fine-grained for TLP)
#define SCHUNK 16           // S per chunk

typedef _Float16 f16_t;
typedef _Float16 f16x8 __attribute__((ext_vector_type(8)));
typedef _Float16 f16x2 __attribute__((ext_vector_type(2)));
typedef float f32x4 __attribute__((ext_vector_type(4)));

__device__ __forceinline__ float2 cmul(float2 a, float2 b) {
  return make_float2(a.x * b.x - a.y * b.y, a.x * b.y + a.y * b.x);
}

// Async global->LDS 16B copy (m97: width=16 emits global_load_lds_dwordx4).
__device__ __forceinline__ void async_cp16(const void* g, void* l) {
  __builtin_amdgcn_global_load_lds(
      (const __attribute__((address_space(1))) void*)g,
      (__attribute__((address_space(3))) void*)l, 16, 0, 0);
}

// Counted vmcnt waits (T4): literal immediates via specialization.
template <int N> __device__ __forceinline__ void vwait();
template <> __device__ __forceinline__ void vwait<0>() { asm volatile("s_waitcnt vmcnt(0)" ::: "memory"); }
template <> __device__ __forceinline__ void vwait<1>() { asm volatile("s_waitcnt vmcnt(1)" ::: "memory"); }
template <> __device__ __forceinline__ void vwait<2>() { asm volatile("s_waitcnt vmcnt(2)" ::: "memory"); }
template <> __device__ __forceinline__ void vwait<3>() { asm volatile("s_waitcnt vmcnt(3)" ::: "memory"); }
template <> __device__ __forceinline__ void vwait<4>() { asm volatile("s_waitcnt vmcnt(4)" ::: "memory"); }
template <> __device__ __forceinline__ void vwait<5>() { asm volatile("s_waitcnt vmcnt(5)" ::: "memory"); }
template <> __device__ __forceinline__ void vwait<6>() { asm volatile("s_waitcnt vmcnt(6)" ::: "memory"); }

// Branchless erf-based gelu, A&S 7.1.26 (|eps_erf| <= 1.5e-7).
__device__ __forceinline__ float fast_gelu(float val) {
  float av = __builtin_fabsf(val);
  float z = av * 0.70710678118654752f;
  float t = __builtin_amdgcn_rcpf(__builtin_fmaf(0.3275911f, z, 1.0f));
  float poly = t * __builtin_fmaf(t,
      __builtin_fmaf(t, __builtin_fmaf(t,
          __builtin_fmaf(t, 1.061405429f, -1.453152027f),
          1.421413741f), -0.284496736f), 0.254829592f);
  float e = __builtin_amdgcn_exp2f(z * z * -1.4426950408889634f);
  float w = poly * e;
  float r = fmaxf(val, 0.0f);
  return __builtin_fmaf(-0.5f * av, w, r);
}

// 1024-pt complex FFT over LDS ping-pong buffers; result lands back in bufA.
__device__ __forceinline__ void fft1024(float2* bufA, float2* bufB,
                                        const float2* tw, int lt) {
  float2* s = bufA;
  float2* d = bufB;
  for (int m = 1; m < 1024; m <<= 1) {
#pragma unroll
    for (int r2 = 0; r2 < 2; ++r2) {
      int u = lt + r2 * 256;
      int k = u & (m - 1);
      int jm = u - k;
      float2 c0 = s[u];
      float2 c1 = s[u + 512];
      float2 wt = tw[jm];
      float2 su = make_float2(c0.x + c1.x, c0.y + c1.y);
      float2 df = make_float2(c0.x - c1.x, c0.y - c1.y);
      float2 pr = cmul(wt, df);
      d[2 * jm + k] = su;
      d[2 * jm + k + m] = pr;
    }
    __syncthreads();
    float2* tmp = s; s = d; d = tmp;
  }
}

// 512-pt complex FFT (one butterfly per thread per stage); returns result ptr.
__device__ __forceinline__ float2* fft512(float2* bufA, float2* bufB,
                                          const float2* tw, int lt) {
  float2* s = bufA;
  float2* d = bufB;
  for (int m = 1; m < 512; m <<= 1) {
    int u = lt;
    int k = u & (m - 1);
    int jm = u - k;
    float2 c0 = s[u];
    float2 c1 = s[u + 256];
    float2 wt = tw[jm];
    float2 su = make_float2(c0.x + c1.x, c0.y + c1.y);
    float2 df = make_float2(c0.x - c1.x, c0.y - c1.y);
    float2 pr = cmul(wt, df);
    d[2 * jm + k] = su;
    d[2 * jm + k + m] = pr;
    __syncthreads();
    float2* tmp = s; s = d; d = tmp;
  }
  return s;   // 9 stages -> result in bufB
}

// ---------------------------------------------------------------------------
// Weight-row FFT, PACKED-REAL (R10-validated): each complex 1024-FFT carries
// TWO real rows.  768 blocks for 3072 weight rows + 1 block for biases.
// ---------------------------------------------------------------------------
__global__ __launch_bounds__(512) void wfft_k(
    const float* __restrict__ Wq, const float* __restrict__ Wk,
    const float* __restrict__ Wv, const float* __restrict__ bq,
    const float* __restrict__ bk, const float* __restrict__ bv,
    float* __restrict__ WfAll, float* __restrict__ biasC) {
  __shared__ float2 tw[512];
  __shared__ float2 bufA[2][1024];
  __shared__ float2 bufB[2][1024];
  const int tid = threadIdx.x;
  const int rh = tid >> 8;          // slot within block: 0/1
  const int lt = tid & 255;
  const int slot = blockIdx.x * 2 + rh;   // 0..1537
  const float *src0, *src1;
  float *dstA, *dstB = nullptr;
  bool storeB = true;
  if (slot < 1536) {
    const int p = slot >> 9;        // 512 slots (1024 rows) per projection
    const int j = slot & 511;
    const float* W = (p == 0) ? Wq : ((p == 1) ? Wk : Wv);
    src0 = W + (size_t)(2 * j) * DD;
    src1 = W + (size_t)(2 * j + 1) * DD;
    dstA = WfAll + ((size_t)p * DD + 2 * j) * WFP;
    dstB = WfAll + ((size_t)p * DD + 2 * j + 1) * WFP;
  } else if (slot == 1536) {
    src0 = bq; src1 = bk;
    dstA = biasC;
    dstB = biasC + WFP;
  } else {
    src0 = bv; src1 = bv;            // self-packed: A-part = rfft(bv) exactly
    dstA = biasC + 2 * (size_t)WFP;
    storeB = false;
  }
  if (rh == 0) {
    for (int t = lt; t < 512; t += 256) {
      float ang = -6.2831853071795864769f * (float)t * (1.0f / 1024.0f);
      tw[t] = make_float2(cosf(ang), sinf(ang));
    }
  }
  for (int t = lt; t < 1024; t += 256)
    bufA[rh][t] = make_float2(src0[t], src1[t]);
  __syncthreads();
  fft1024(bufA[rh], bufB[rh], tw, lt);
  // unpack Hermitian halves
  for (int k = lt; k <= 512; k += 256) {
    const int nk = (1024 - k) & 1023;
    const float2 zk = bufA[rh][k];
    const float2 zn = bufA[rh][nk];
    dstA[2 * k]     = 0.5f * (zk.x + zn.x);
    dstA[2 * k + 1] = 0.5f * (zk.y - zn.y);
    if (storeB) {
      dstB[2 * k]     = 0.5f * (zk.y + zn.y);
      dstB[2 * k + 1] = 0.5f * (zn.x - zk.x);
    }
  }
  for (int j = 1026 + lt; j < WFP; j += 256) {
    dstA[j] = 0.f;
    if (storeB) dstB[j] = 0.f;
  }
}

// ---------------------------------------------------------------------------
// QKV transpose + cast: all 3 projections in one launch (z = projection).
// ---------------------------------------------------------------------------
__global__ __launch_bounds__(256) void transpose_cast_qkv_k(
    const float* __restrict__ WfAll, f16_t* __restrict__ BtH) {
  __shared__ float tile[32][33];
  const int tx = threadIdx.x & 31, ty = threadIdx.x >> 5;  // 32 x 8
  const int n0 = blockIdx.x * 32, k0 = blockIdx.y * 32;
  const int pp = blockIdx.z;
  const float* W = WfAll + (size_t)pp * DD * WFP;
  f16_t* Wt = BtH + (size_t)pp * WFP * DD;
#pragma unroll
  for (int i = 0; i < 32; i += 8)
    tile[ty + i][tx] = W[(size_t)(k0 + ty + i) * WFP + n0 + tx];
  __syncthreads();
#pragma unroll
  for (int i = 0; i < 32; i += 8)
    Wt[(size_t)(n0 + ty + i) * DD + k0 + tx] = (f16_t)tile[tx][ty + i];
}

// MLP transposes: W1 (z=0) and W2 (z=1) in one launch, role-swapped mapping.
__global__ __launch_bounds__(256) void transpose_mlp_k(
    const float* __restrict__ W1, f16_t* __restrict__ W1T,
    const float* __restrict__ W2, f16_t* __restrict__ W2T) {
  __shared__ float tile[32][33];
  const int tx = threadIdx.x & 31, ty = threadIdx.x >> 5;  // 32 x 8
  const float* W; f16_t* Wt; int K, N, n0, k0;
  if (blockIdx.z == 0) {         // W1: K=1024, N=4096; grid x=128 n, y=32 k
    W = W1; Wt = W1T; K = DD; N = NHID;
    n0 = blockIdx.x * 32; k0 = blockIdx.y * 32;
  } else {                       // W2: K=4096, N=1024; x=128 k, y=32 n
    W = W2; Wt = W2T; K = NHID; N = DD;
    n0 = blockIdx.y * 32; k0 = blockIdx.x * 32;
  }
#pragma unroll
  for (int i = 0; i < 32; i += 8)
    tile[ty + i][tx] = W[(size_t)(k0 + ty + i) * N + n0 + tx];
  __syncthreads();
#pragma unroll
  for (int i = 0; i < 32; i += 8)
    Wt[(size_t)(n0 + ty + i) * K + k0 + tx] = (f16_t)tile[tx][ty + i];
}

// ---------------------------------------------------------------------------
// LayerNorm (fp32 in) -> fp16.  One block per row of 1024.
// ---------------------------------------------------------------------------
__global__ __launch_bounds__(256) void ln_cast_k(
    const float* __restrict__ x, const float* __restrict__ g,
    const float* __restrict__ b, f16_t* __restrict__ hH) {
  const int row = blockIdx.x, tid = threadIdx.x;
  __shared__ float red[8];
  const float* xr = x + (size_t)row * DD;
  float v[4], ls = 0.f, lq = 0.f;
#pragma unroll
  for (int i = 0; i < 4; ++i) {
    v[i] = xr[i * 256 + tid];
    ls += v[i];
    lq += v[i] * v[i];
  }
#pragma unroll
  for (int o = 32; o > 0; o >>= 1) {
    ls += __shfl_down(ls, o);
    lq += __shfl_down(lq, o);
  }
  const int lane = tid & 63, w = tid >> 6;
  if (lane == 0) { red[w] = ls; red[w + 4] = lq; }
  __syncthreads();
  const float S = red[0] + red[1] + red[2] + red[3];
  const float Q = red[4] + red[5] + red[6] + red[7];
  const float mean = S * (1.f / 1024.f);
  const float var = Q * (1.f / 1024.f) - mean * mean;
  const float rs = rsqrtf(var + 1e-5f);
#pragma unroll
  for (int i = 0; i < 4; ++i) {
    int n = i * 256 + tid;
    float val = (v[i] - mean) * rs * g[n] + b[n];
    hH[(size_t)row * DD + n] = (f16_t)val;
  }
}

// ---------------------------------------------------------------------------
// QKV GEMM, uniform fp16 in / fp32 out: M=8192, N=3456, K=1024.  128x128
// tile, 32 KB LDS, m97-style staging loop, XCD snake, 1728 blocks, 3/CU.
// ---------------------------------------------------------------------------
__global__ __launch_bounds__(256, 3) void gemm_qkv_k(
    const f16_t* __restrict__ A, const f16_t* __restrict__ Bt,
    const float* __restrict__ bias, float* __restrict__ outF) {
  __shared__ alignas(16) f16_t AsH[128 * 64];
  __shared__ alignas(16) f16_t BsH[128 * 64];
  const int tid = threadIdx.x;
  const int lane = tid & 63;
  const int w = tid >> 6;
  const int wm = w >> 1, wn = w & 1;

  const int lin = blockIdx.x;
  const int s = (lin & 7) * 216 + (lin >> 3);
  const int g = s / 108;
  const int r = s % 108;
  const int n = r >> 2;
  const int m0 = g * 4 + (r & 3);
  const int bn = n * 128;
  const int bm = m0 * 128;

  f32x4 acc[4][4];
#pragma unroll
  for (int i = 0; i < 4; ++i)
#pragma unroll
    for (int j = 0; j < 4; ++j) acc[i][j] = (f32x4){0.f, 0.f, 0.f, 0.f};

  const int srow = lane >> 3;
  const int slot = lane & 7;

  for (int kt = 0; kt < 1024; kt += 64) {
#pragma unroll
    for (int i = 0; i < 4; ++i) {
      const int rb = (i * 4 + w) * 8;
      const int row = rb + srow;
      const int gg = (slot - (row & 7)) & 7;
      size_t ga = (size_t)(bm + row) * 1024 + kt + gg * 8;
      size_t gb = (size_t)(bn + row) * 1024 + kt + gg * 8;
      async_cp16(A + ga, &AsH[rb * 64]);
      async_cp16(Bt + gb, &BsH[rb * 64]);
    }
    __syncthreads();
#pragma unroll
    for (int ks = 0; ks < 2; ++ks) {
      const int cgbase = ks * 4 + (lane >> 4);
      f16x8 ah[4], bh[4];
#pragma unroll
      for (int mt = 0; mt < 4; ++mt) {
        int m = wm * 64 + mt * 16 + (lane & 15);
        int sl = (cgbase + (m & 7)) & 7;
        ah[mt] = *(const f16x8*)(&AsH[m * 64 + sl * 8]);
      }
#pragma unroll
      for (int nt = 0; nt < 4; ++nt) {
        int nn = wn * 64 + nt * 16 + (lane & 15);
        int sl = (cgbase + (nn & 7)) & 7;
        bh[nt] = *(const f16x8*)(&BsH[nn * 64 + sl * 8]);
      }
#pragma unroll
      for (int mt = 0; mt < 4; ++mt)
#pragma unroll
        for (int nt = 0; nt < 4; ++nt)
          acc[mt][nt] = __builtin_amdgcn_mfma_f32_16x16x32_f16(
              ah[mt], bh[nt], acc[mt][nt], 0, 0, 0);
    }
    __syncthreads();
  }

  const int q = lane >> 4;
  const int cn = lane & 15;
#pragma unroll
  for (int mt = 0; mt < 4; ++mt) {
#pragma unroll
    for (int nt = 0; nt < 4; ++nt) {
      const int gcol = bn + wn * 64 + nt * 16 + cn;
      const float bv = bias[gcol];
      const int grow0 = bm + wm * 64 + mt * 16 + q * 4;
#pragma unroll
      for (int i = 0; i < 4; ++i) {
        size_t idx = (size_t)(grow0 + i) * NQKV + gcol;
        outF[idx] = acc[mt][nt][i] + bv;
      }
    }
  }
}

// ---------------------------------------------------------------------------
// 8-phase GEMM building blocks.
// ---------------------------------------------------------------------------
template <int RHALF>
__device__ __forceinline__ void stage_half(const f16_t* __restrict__ G,
                                           int grow0, int ldk, int kt,
                                           f16_t* ls, int w, int lane) {
  const int srow = lane >> 3;
  const int slot = lane & 7;
#pragma unroll
  for (int j = 0; j < RHALF / 64; ++j) {
    const int rb = (w + j * 8) * 8;           // row block within half
    const int row = rb + srow;
    const int gg = (slot - (row & 7)) & 7;    // pre-swizzled global col-group
    async_cp16(G + (size_t)(grow0 + row) * ldk + kt + gg * 8, ls + rb * 64);
  }
}

template <int BM, int BN>
__device__ __forceinline__ void readA(const f16_t* As, int mq, int wm, int lane,
                                      f16x8 (&aR)[BM / 64][2]) {
#pragma unroll
  for (int mf = 0; mf < BM / 64; ++mf) {
    const int m = mq * (BM / 2) + wm * (BM / 4) + mf * 16 + (lane & 15);
#pragma unroll
    for (int ks = 0; ks < 2; ++ks) {
      const int cg = ks * 4 + (lane >> 4);
      const int sl = (cg + (m & 7)) & 7;
      aR[mf][ks] = *(const f16x8*)(As + m * 64 + sl * 8);
    }
  }
}

template <int BM, int BN>
__device__ __forceinline__ void readB(const f16_t* Bs, int nq, int wn, int lane,
                                      f16x8 (&bR)[BN / 128][2]) {
#pragma unroll
  for (int nf = 0; nf < BN / 128; ++nf) {
    const int n = nq * (BN / 2) + wn * (BN / 8) + nf * 16 + (lane & 15);
#pragma unroll
    for (int ks = 0; ks < 2; ++ks) {
      const int cg = ks * 4 + (lane >> 4);
      const int sl = (cg + (n & 7)) & 7;
      bR[nf][ks] = *(const f16x8*)(Bs + n * 64 + sl * 8);
    }
  }
}

template <int MF, int NF>
__device__ __forceinline__ void mfma_q(f32x4 (&acc)[MF][NF],
                                       const f16x8 (&aR)[MF][2],
                                       const f16x8 (&bR)[NF][2]) {
#pragma unroll
  for (int ks = 0; ks < 2; ++ks)
#pragma unroll
    for (int mf = 0; mf < MF; ++mf)
#pragma unroll
      for (int nf = 0; nf < NF; ++nf)
        acc[mf][nf] = __builtin_amdgcn_mfma_f32_16x16x32_f16(
            aR[mf][ks], bR[nf][ks], acc[mf][nf], 0, 0, 0);
}

// ---------------------------------------------------------------------------
// MLP GEMM, faithful m201 two-tile/8-phase schedule: 2 K-tiles per iter,
// one half-tile staged per phase at 3-half-tile depth, vmcnt(LA+2*LB) only
// at phases 4 and 8.  Stage order per iter: A1(t1), A0(t2), B0(t2), B1(t2),
// A1(t2), A0(t3), B0(t3), B1(t3).  FIFO retire analysis guarantees each
// phase's LDS operands landed; each region is staged >=1 barrier after its
// last ds_read.  EPI 1: fast-gelu -> fp16.  EPI 2: +bias+resid -> fp32.
// ---------------------------------------------------------------------------
template <int BM, int BN, int MM, int NN, int KK, int EPI>
__global__ __launch_bounds__(512, 2) void gemm8p_k(
    const f16_t* __restrict__ A, const f16_t* __restrict__ Bt,
    const float* __restrict__ bias, const float* __restrict__ resid,
    float* __restrict__ outF, f16_t* __restrict__ outH) {
  constexpr int MF = BM / 64;      // M-frags per quadrant
  constexpr int NF = BN / 128;     // N-frags per quadrant
  constexpr int LA = BM / 128;     // loads/thread per A-half
  constexpr int LB = BN / 128;     // loads/thread per B-half
  constexpr int NT = KK / 64;
  constexpr int NI = NT / 2;       // iterations (2 K-tiles each)
  constexpr int WAITN = LA + 2 * LB;
  constexpr int HT = (BM + BN) * 64;
  __shared__ alignas(16) f16_t lds[2 * HT];

  const int tid = threadIdx.x;
  const int lane = tid & 63;
  const int w = tid >> 6;          // 8 waves
  const int wm = w >> 2;           // 0..1
  const int wn = w & 3;            // 0..3

  constexpr int ntm = MM / BM, ntn = NN / BN;
  constexpr int per = (ntm * ntn) / 8;
  const int lin = (int)blockIdx.x;
  const int s = (lin & 7) * per + (lin >> 3);
  const int bn = (s % ntn) * BN;
  const int bm = (s / ntn) * BM;

  f16_t* EA = lds;              f16_t* EB = lds + BM * 64;
  f16_t* OA = lds + HT;         f16_t* OB = lds + HT + BM * 64;

  f32x4 acc[2][2][MF][NF];
#pragma unroll
  for (int a0 = 0; a0 < 2; ++a0)
#pragma unroll
    for (int a1 = 0; a1 < 2; ++a1)
#pragma unroll
      for (int mf = 0; mf < MF; ++mf)
#pragma unroll
        for (int nf = 0; nf < NF; ++nf)
          acc[a0][a1][mf][nf] = (f32x4){0.f, 0.f, 0.f, 0.f};

  // prologue: stage t0 fully into E, t1's A0/B0/B1 into O (7 half-tiles);
  // wait retires t0's 4 -> WAITN outstanding (t1's 3) = steady-state invariant.
  stage_half<BM / 2>(A, bm, KK, 0, EA, w, lane);
  stage_half<BN / 2>(Bt, bn, KK, 0, EB, w, lane);
  stage_half<BN / 2>(Bt, bn + BN / 2, KK, 0, EB + (BN / 2) * 64, w, lane);
  stage_half<BM / 2>(A, bm + BM / 2, KK, 0, EA + (BM / 2) * 64, w, lane);
  stage_half<BM / 2>(A, bm, KK, 64, OA, w, lane);
  stage_half<BN / 2>(Bt, bn, KK, 64, OB, w, lane);
  stage_half<BN / 2>(Bt, bn + BN / 2, KK, 64, OB + (BN / 2) * 64, w, lane);
  vwait<WAITN>();
  __builtin_amdgcn_s_barrier();

  f16x8 aR[MF][2], bR0[NF][2], bR1[NF][2];

  for (int i = 0; i < NI; ++i) {
    const bool pre = (i + 1 < NI);
    const int k1 = (2 * i + 1) << 6;
    const int k2 = (2 * i + 2) << 6;
    const int k3 = (2 * i + 3) << 6;

    // ---- ph1: Q(0,0) of E-tile; stage A1(t1)->O ---------------------------
    readA<BM, BN>(EA, 0, wm, lane, aR);
    readB<BM, BN>(EB, 0, wn, lane, bR0);
    stage_half<BM / 2>(A, bm + BM / 2, KK, k1, OA + (BM / 2) * 64, w, lane);
    __builtin_amdgcn_s_barrier();
    __builtin_amdgcn_s_setprio(1);
    mfma_q<MF, NF>(acc[0][0], aR, bR0);
    __builtin_amdgcn_s_setprio(0);
    __builtin_amdgcn_s_barrier();

    // ---- ph2: Q(0,1) of E; stage A0(t2)->E --------------------------------
    readB<BM, BN>(EB, 1, wn, lane, bR1);
    if (pre) stage_half<BM / 2>(A, bm, KK, k2, EA, w, lane);
    __builtin_amdgcn_s_barrier();
    __builtin_amdgcn_s_setprio(1);
    mfma_q<MF, NF>(acc[0][1], aR, bR1);
    __builtin_amdgcn_s_setprio(0);
    __builtin_amdgcn_s_barrier();

    // ---- ph3: Q(1,0) of E; stage B0(t2)->E --------------------------------
    readA<BM, BN>(EA, 1, wm, lane, aR);
    if (pre) stage_half<BN / 2>(Bt, bn, KK, k2, EB, w, lane);
    __builtin_amdgcn_s_barrier();
    __builtin_amdgcn_s_setprio(1);
    mfma_q<MF, NF>(acc[1][0], aR, bR0);
    __builtin_amdgcn_s_setprio(0);
    __builtin_amdgcn_s_barrier();

    // ---- ph4: Q(1,1) of E; stage B1(t2)->E; WAIT --------------------------
    if (pre) stage_half<BN / 2>(Bt, bn + BN / 2, KK, k2,
                                EB + (BN / 2) * 64, w, lane);
    __builtin_amdgcn_s_barrier();
    __builtin_amdgcn_s_setprio(1);
    mfma_q<MF, NF>(acc[1][1], aR, bR1);
    __builtin_amdgcn_s_setprio(0);
    if (pre) vwait<WAITN>(); else vwait<0>();   // retire through A1(t1)
    __builtin_amdgcn_s_barrier();

    // ---- ph5: Q(0,0) of O-tile; stage A1(t2)->E ---------------------------
    readA<BM, BN>(OA, 0, wm, lane, aR);
    readB<BM, BN>(OB, 0, wn, lane, bR0);
    if (pre) stage_half<BM / 2>(A, bm + BM / 2, KK, k2,
                                EA + (BM / 2) * 64, w, lane);
    __builtin_amdgcn_s_barrier();
    __builtin_amdgcn_s_setprio(1);
    mfma_q<MF, NF>(acc[0][0], aR, bR0);
    __builtin_amdgcn_s_setprio(0);
    __builtin_amdgcn_s_barrier();

    // ---- ph6: Q(0,1) of O; stage A0(t3)->O --------------------------------
    readB<BM, BN>(OB, 1, wn, lane, bR1);
    if (pre) stage_half<BM / 2>(A, bm, KK, k3, OA, w, lane);
    __builtin_amdgcn_s_barrier();
    __builtin_amdgcn_s_setprio(1);
    mfma_q<MF, NF>(acc[0][1], aR, bR1);
    __builtin_amdgcn_s_setprio(0);
    __builtin_amdgcn_s_barrier();

    // ---- ph7: Q(1,0) of O; stage B0(t3)->O --------------------------------
    readA<BM, BN>(OA, 1, wm, lane, aR);
    if (pre) stage_half<BN / 2>(Bt, bn, KK, k3, OB, w, lane);
    __builtin_amdgcn_s_barrier();
    __builtin_amdgcn_s_setprio(1);
    mfma_q<MF, NF>(acc[1][0], aR, bR0);
    __builtin_amdgcn_s_setprio(0);
    __builtin_amdgcn_s_barrier();

    // ---- ph8: Q(1,1) of O; stage B1(t3)->O; WAIT --------------------------
    if (pre) stage_half<BN / 2>(Bt, bn + BN / 2, KK, k3,
                                OB + (BN / 2) * 64, w, lane);
    __builtin_amdgcn_s_barrier();
    __builtin_amdgcn_s_setprio(1);
    mfma_q<MF, NF>(acc[1][1], aR, bR1);
    __builtin_amdgcn_s_setprio(0);
    if (pre) vwait<WAITN>();                    // retire through A1(t2)
    __builtin_amdgcn_s_barrier();
  }

  const int q4 = lane >> 4;
  const int cn = lane & 15;
#pragma unroll
  for (int mq = 0; mq < 2; ++mq)
#pragma unroll
    for (int nq = 0; nq < 2; ++nq)
#pragma unroll
      for (int mf = 0; mf < MF; ++mf)
#pragma unroll
        for (int nf = 0; nf < NF; ++nf) {
          const int gcol = bn + nq * (BN / 2) + wn * (BN / 8) + nf * 16 + cn;
          const float bv = bias[gcol];
          const int grow0 = bm + mq * (BM / 2) + wm * (BM / 4) + mf * 16 + q4 * 4;
#pragma unroll
          for (int i = 0; i < 4; ++i) {
            const float val = acc[mq][nq][mf][nf][i] + bv;
            const size_t idx = (size_t)(grow0 + i) * NN + gcol;
            if (EPI == 1) {
              outH[idx] = (f16_t)fast_gelu(val);
            } else {
              outF[idx] = val + resid[idx];
            }
          }
        }
}

// ---------------------------------------------------------------------------
// Inline normalize helpers reading raw fp32 bins from qkv_f rows (1728
// float2 bins: q at [f], k at [576+f], v at [1152+f]).
// ---------------------------------------------------------------------------
__device__ __forceinline__ float2 unitc(float2 a) {
  float inv = 1.0f / fmaxf(sqrtf(a.x * a.x + a.y * a.y), 1e-8f);
  return make_float2(a.x * inv, a.y * inv);
}
__device__ __forceinline__ float2 bind_bin(const float2* r, int f) {
  float2 kn = unitc(r[576 + f]);
  float2 vn = unitc(r[1152 + f]);
  return cmul(kn, vn);
}

// ---------------------------------------------------------------------------
// 3-pass parallel prefix sum over S per (batch, bin).  Fine chunks
// (NCHUNK=128, SCHUNK=16): 1024-block grids, 16-deep serial chains.
// ---------------------------------------------------------------------------
__global__ __launch_bounds__(256) void scan_pass1_k(
    const float* __restrict__ qkvF, float2* __restrict__ T) {
  const int bid = blockIdx.x;
  const int sc = bid & (NCHUNK - 1);
  const int fh = (bid >> 7) & 1;
  const int b = bid >> 8;
  const int s0 = sc * SCHUNK;
  const float2* base = (const float2*)(qkvF + ((size_t)(b * SSEQ + s0)) * NQKV);
  for (int f = fh * 256 + threadIdx.x; f < FBINS; f += 512) {
    float2 acc = make_float2(0.f, 0.f);
    const float2* r = base;
    for (int i = 0; i < SCHUNK; ++i) {
      float2 pv = bind_bin(r, f);
      acc.x += pv.x; acc.y += pv.y;
      r += NQKV / 2;
    }
    T[((size_t)b * NCHUNK + sc) * FBINS + f] = acc;
  }
}

// One wave per (batch, bin); lane l owns chunk pair (2l, 2l+1).
__global__ __launch_bounds__(256) void scan_pass2_k(float2* __restrict__ T) {
  const int wv = threadIdx.x >> 6, lane = threadIdx.x & 63;
  const int bin = blockIdx.x * 4 + wv;      // 0..2051 == NB*FBINS-1 exactly
  const int b = bin / FBINS, f = bin % FBINS;
  const size_t a0 = ((size_t)b * NCHUNK + 2 * lane) * FBINS + f;
  const size_t a1 = ((size_t)b * NCHUNK + 2 * lane + 1) * FBINS + f;
  float2 c0 = T[a0];
  float2 c1 = T[a1];
  float2 v = make_float2(c0.x + c1.x, c0.y + c1.y);
  // Kogge-Stone inclusive scan of pair-sums across 64 lanes
#pragma unroll
  for (int o = 1; o < 64; o <<= 1) {
    float vx = __shfl_up(v.x, o);
    float vy = __shfl_up(v.y, o);
    if (lane >= o) { v.x += vx; v.y += vy; }
  }
  // exclusive pair offset
  float ex = __shfl_up(v.x, 1);
  float ey = __shfl_up(v.y, 1);
  if (lane == 0) { ex = 0.f; ey = 0.f; }
  T[a0] = make_float2(ex, ey);
  T[a1] = make_float2(ex + c0.x, ey + c0.y);
}

__global__ __launch_bounds__(256) void scan_pass3_k(
    const float* __restrict__ qkvF, const float2* __restrict__ T,
    float2* __restrict__ Scum) {
  const int bid = blockIdx.x;
  const int sc = bid & (NCHUNK - 1);
  const int fh = (bid >> 7) & 1;
  const int b = bid >> 8;
  const int s0 = sc * SCHUNK;
  const float2* base = (const float2*)(qkvF + ((size_t)(b * SSEQ + s0)) * NQKV);
  for (int f = fh * 256 + threadIdx.x; f < FBINS; f += 512) {
    float2 acc = T[((size_t)b * NCHUNK + sc) * FBINS + f];
    const float2* r = base;
    size_t orow = ((size_t)(b * SSEQ + s0)) * FPAD + f;
    for (int i = 0; i < SCHUNK; ++i) {
      float2 pv = bind_bin(r, f);
      acc.x += pv.x; acc.y += pv.y;
      Scum[orow] = acc;
      r += NQKV / 2;
      orow += FPAD;
    }
  }
}

// ---------------------------------------------------------------------------
// Unbind + LN2, 2 rows per 512-thread block (R4-proven version).
// ---------------------------------------------------------------------------
__global__ __launch_bounds__(512) void unbind_ln2_k(
    const float2* __restrict__ Scum, const float* __restrict__ qkvF,
    const float* __restrict__ x, float* __restrict__ x2out,
    f16_t* __restrict__ h2, const float* __restrict__ g2,
    const float* __restrict__ b2) {
  __shared__ float2 tw[256];     // e^{+2pi i t/512}
  __shared__ float2 Marr[2][513];
  __shared__ float2 bufA[2][512];
  __shared__ float2 bufB[2][512];
  __shared__ float red[2][8];
  const int tid = threadIdx.x;
  const int rh = tid >> 8;       // row half 0/1
  const int lt = tid & 255;
  const int row = blockIdx.x * 2 + rh;

  if (rh == 0) {
    float ang = 6.2831853071795864769f * (float)lt * (1.0f / 512.0f);
    tw[lt] = make_float2(cosf(ang), sinf(ang));
  }
  const float2* qrow = (const float2*)(qkvF + (size_t)row * NQKV);
  for (int t = lt; t <= 512; t += 256) {
    float2 sc = Scum[(size_t)row * FPAD + t];
    float2 fq = unitc(qrow[t]);
    Marr[rh][t] = make_float2(sc.x * fq.x + sc.y * fq.y,
                              sc.y * fq.x - sc.x * fq.y);
  }
  __syncthreads();
  // build Z into bufA
#pragma unroll
  for (int rr = 0; rr < 2; ++rr) {
    int t = lt + rr * 256;
    float2 a = Marr[rh][t];
    float2 b = Marr[rh][512 - t];
    float2 E = make_float2(0.5f * (a.x + b.x), 0.5f * (a.y - b.y));
    float2 Dd = make_float2(0.5f * (a.x - b.x), 0.5f * (a.y + b.y));
    float ang = 6.2831853071795864769f * (float)t * (1.0f / 1024.0f);
    float cw = cosf(ang), sw = sinf(ang);
    float2 O = make_float2(cw * Dd.x - sw * Dd.y, cw * Dd.y + sw * Dd.x);
    bufA[rh][t] = make_float2(E.x - O.y, E.y + O.x);
  }
  __syncthreads();
  float2* res = fft512(bufA[rh], bufB[rh], tw, lt);

  const float* xr = x + (size_t)row * DD;
  float v[2][2];
  float ls = 0.f, lq = 0.f;
#pragma unroll
  for (int rr = 0; rr < 2; ++rr) {
    int n = lt + rr * 256;
    float2 z = res[n];
    float2 xv = *(const float2*)(xr + 2 * n);
    float v0 = xv.x + z.x * (1.0f / 512.0f);
    float v1 = xv.y + z.y * (1.0f / 512.0f);
    *(float2*)(x2out + (size_t)row * DD + 2 * n) = make_float2(v0, v1);
    v[rr][0] = v0; v[rr][1] = v1;
    ls += v0 + v1;
    lq += v0 * v0 + v1 * v1;
  }
#pragma unroll
  for (int o = 32; o > 0; o >>= 1) {
    ls += __shfl_down(ls, o);
    lq += __shfl_down(lq, o);
  }
  const int lane = tid & 63, w4 = (tid >> 6) & 3;
  if (lane == 0) { red[rh][w4] = ls; red[rh][w4 + 4] = lq; }
  __syncthreads();
  const float S = red[rh][0] + red[rh][1] + red[rh][2] + red[rh][3];
  const float Q = red[rh][4] + red[rh][5] + red[rh][6] + red[rh][7];
  const float mean = S * (1.f / 1024.f);
  const float var = Q * (1.f / 1024.f) - mean * mean;
  const float rs = rsqrtf(var + 1e-5f);
  f16_t* hr = h2 + (size_t)row * DD;
#pragma unroll
  for (int rr = 0; rr < 2; ++rr) {
    int n = lt + rr * 256;
    float2 gv = *(const float2*)(g2 + 2 * n);
    float2 bv = *(const float2*)(b2 + 2 * n);
    f16x2 hp;
    hp[0] = (f16_t)((v[rr][0] - mean) * rs * gv.x + bv.x);
    hp[1] = (f16_t)((v[rr][1] - mean) * rs * gv.y + bv.y);
    *(f16x2*)(hr + 2 * n) = hp;
  }
}

// ---------------------------------------------------------------------------
extern "C" void kernel_launch(void* const* d_in, const int* in_sizes, int n_in,
                              void* d_out, int out_size, void* d_ws,
                              size_t ws_size, hipStream_t stream) {
  const float* x     = (const float*)d_in[0];
  const float* Wq    = (const float*)d_in[1];
  const float* bq    = (const float*)d_in[2];
  const float* Wk    = (const float*)d_in[3];
  const float* bk    = (const float*)d_in[4];
  const float* Wv    = (const float*)d_in[5];
  const float* bv    = (const float*)d_in[6];
  const float* ln1_g = (const float*)d_in[7];
  const float* ln1_b = (const float*)d_in[8];
  const float* ln2_g = (const float*)d_in[9];
  const float* ln2_b = (const float*)d_in[10];
  const float* W1    = (const float*)d_in[11];
  const float* b1    = (const float*)d_in[12];
  const float* W2    = (const float*)d_in[13];
  const float* b2    = (const float*)d_in[14];
  float* out = (float*)d_out;

  char* p = (char*)d_ws;
  auto take = [&](size_t bytes) {
    char* r = p;
    p += (bytes + 255) & ~(size_t)255;
    return r;
  };
  f16_t* BtH   = (f16_t*)take((size_t)NQKV * DD * sizeof(f16_t));
  f16_t* W1T   = (f16_t*)take((size_t)NHID * DD * sizeof(f16_t));
  f16_t* W2T   = (f16_t*)take((size_t)DD * NHID * sizeof(f16_t));
  float* biasC = (float*)take((size_t)NQKV * sizeof(float));
  f16_t* hbuf  = (f16_t*)take((size_t)MROWS * DD * sizeof(f16_t));   // h, then h2
  char*  big   = take((size_t)MROWS * NQKV * sizeof(float));         // WfAll, qkvF, mlp1
  float2* Scum = (float2*)take((size_t)MROWS * FPAD * sizeof(float2));
  float* x2    = (float*)take((size_t)MROWS * DD * sizeof(float));
  float2* Tch  = (float2*)take((size_t)NB * NCHUNK * FBINS * sizeof(float2));
  // time-disjoint aliases within big:
  float* WfAll   = (float*)big;                 // prep phase only
  float* qkv_f   = (float*)big;                 // fp32 bins (113 MB)
  f16_t* mlp1    = (f16_t*)big;                 // qkv_f dead before MLP1 writes

  // 1. FFT weight rows (packed-real, 2 rows/FFT) + biases -> WfAll, biasC
  wfft_k<<<769, 512, 0, stream>>>(Wq, Wk, Wv, bq, bk, bv, WfAll, biasC);
  // 2. transpose + cast -> BtH (3456 x 1024)  [single launch, z = projection]
  transpose_cast_qkv_k<<<dim3(WFP / 32, DD / 32, 3), 256, 0, stream>>>(
      WfAll, BtH);
  // 3. MLP weights -> transposed fp16 (W1 and W2 in one launch)
  transpose_mlp_k<<<dim3(128, 32, 2), 256, 0, stream>>>(W1, W1T, W2, W2T);

  // 4. h = LN1(x) -> fp16
  ln_cast_k<<<MROWS, 256, 0, stream>>>(x, ln1_g, ln1_b, hbuf);

  // 5. Fourier bins (fp32): qkv_f = h @ rfft_rows(W)^T + rfft(bias)
  gemm_qkv_k<<<(NQKV / 128) * (MROWS / 128), 256, 0, stream>>>(
      hbuf, BtH, biasC, qkv_f);

  // 6. causal prefix sum over S (fine chunks)
  scan_pass1_k<<<NB * NCHUNK * 2, 256, 0, stream>>>(qkv_f, Tch);
  scan_pass2_k<<<(NB * FBINS) / 4, 256, 0, stream>>>(Tch);
  scan_pass3_k<<<NB * NCHUNK * 2, 256, 0, stream>>>(qkv_f, Tch, Scum);

  // 7. unbind (packed real iFFT) + residual + LN2   [2 rows/block]
  unbind_ln2_k<<<MROWS / 2, 512, 0, stream>>>(Scum, qkv_f, x, x2, hbuf,
                                              ln2_g, ln2_b);

  // 8. mlp1 = gelu(h2 @ W1 + b1)   [two-tile 8-phase 256x256, 512 blocks]
  gemm8p_k<256, 256, MROWS, NHID, DD, 1><<<512, 512, 0, stream>>>(
      hbuf, W1T, b1, nullptr, nullptr, mlp1);

  // 9. out = x2 + mlp1 @ W2 + b2  [two-tile 8-phase 128x256, 256 blocks]
  gemm8p_k<128, 256, MROWS, DD, NHID, 2><<<256, 512, 0, stream>>>(
      mlp1, W2T, b2, x2, out, nullptr);
}